// Round 1
// baseline (3197.641 us; speedup 1.0000x reference)
//
#include <hip/hip_runtime.h>
#include <cmath>

// ---------------------------------------------------------------------------
// Generic tiled NT GEMM: C[M,N] = A[M,K] * B[N,K]^T
// A row-major lda, B row-major ldb (K inner for both), C row-major ldc.
// BM=BN=128, BK=8, 256 threads, 8x8 per thread. Requires M%128==0, K%8==0.
// N bounds-checked (for the skinny N=96 x_proj GEMM).
// ---------------------------------------------------------------------------
__global__ __launch_bounds__(256)
void gemm_nt(const float* __restrict__ A, const float* __restrict__ B,
             float* __restrict__ C, int M, int N, int K,
             int lda, int ldb, int ldc)
{
    __shared__ float As[8][132];
    __shared__ float Bs[8][132];

    const int tid  = threadIdx.x;
    const int row0 = blockIdx.y * 128;
    const int col0 = blockIdx.x * 128;

    const int lr = tid >> 1;         // 0..127: tile row (A) / tile col (B)
    const int lk = (tid & 1) * 4;    // 0 or 4: k sub-offset

    const int ty = tid >> 4;         // 0..15
    const int tx = tid & 15;         // 0..15

    float acc[8][8];
    #pragma unroll
    for (int i = 0; i < 8; ++i)
        #pragma unroll
        for (int j = 0; j < 8; ++j) acc[i][j] = 0.f;

    for (int k0 = 0; k0 < K; k0 += 8) {
        float4 av = *(const float4*)(A + (size_t)(row0 + lr) * lda + k0 + lk);
        float4 bv = make_float4(0.f, 0.f, 0.f, 0.f);
        const int brow = col0 + lr;
        if (brow < N)
            bv = *(const float4*)(B + (size_t)brow * ldb + k0 + lk);

        __syncthreads();   // previous iteration's compute done before overwrite
        As[lk + 0][lr] = av.x; As[lk + 1][lr] = av.y;
        As[lk + 2][lr] = av.z; As[lk + 3][lr] = av.w;
        Bs[lk + 0][lr] = bv.x; Bs[lk + 1][lr] = bv.y;
        Bs[lk + 2][lr] = bv.z; Bs[lk + 3][lr] = bv.w;
        __syncthreads();

        #pragma unroll
        for (int k = 0; k < 8; ++k) {
            float4 a0 = *(const float4*)&As[k][ty * 8];
            float4 a1 = *(const float4*)&As[k][ty * 8 + 4];
            float4 b0 = *(const float4*)&Bs[k][tx * 8];
            float4 b1 = *(const float4*)&Bs[k][tx * 8 + 4];
            float a[8] = {a0.x, a0.y, a0.z, a0.w, a1.x, a1.y, a1.z, a1.w};
            float b[8] = {b0.x, b0.y, b0.z, b0.w, b1.x, b1.y, b1.z, b1.w};
            #pragma unroll
            for (int i = 0; i < 8; ++i)
                #pragma unroll
                for (int j = 0; j < 8; ++j)
                    acc[i][j] = fmaf(a[i], b[j], acc[i][j]);
        }
    }

    #pragma unroll
    for (int i = 0; i < 8; ++i) {
        const int r = row0 + ty * 8 + i;
        #pragma unroll
        for (int j = 0; j < 8; ++j) {
            const int c = col0 + tx * 8 + j;
            if (c < N) C[(size_t)r * ldc + c] = acc[i][j];
        }
    }
}

// ---------------------------------------------------------------------------
// Causal depthwise conv1d (width 4) + bias + SiLU.
// xz: (B, L, 2*dinner); uses first dinner columns (xr). xc out: (B, L, dinner).
// One thread per 4 consecutive channels.
// ---------------------------------------------------------------------------
__global__ __launch_bounds__(256)
void conv_silu(const float* __restrict__ xz, const float* __restrict__ cw,
               const float* __restrict__ cb, float* __restrict__ xc,
               int Bsz, int L, int dinner)
{
    const int nv = dinner / 4;
    const int g  = blockIdx.x * blockDim.x + threadIdx.x;
    const int d4 = (g % nv) * 4;
    const int t  = (g / nv) % L;
    const int b  = g / (nv * L);
    if (b >= Bsz) return;

    const int ldxz = 2 * dinner;
    // taps for the 4 channels: cw[d][k], row-major (dinner,4)
    float4 w0 = *(const float4*)(cw + (size_t)(d4 + 0) * 4);
    float4 w1 = *(const float4*)(cw + (size_t)(d4 + 1) * 4);
    float4 w2 = *(const float4*)(cw + (size_t)(d4 + 2) * 4);
    float4 w3 = *(const float4*)(cw + (size_t)(d4 + 3) * 4);
    float4 acc = *(const float4*)(cb + d4);

    const float* base = xz + (size_t)b * L * ldxz + d4;
    #pragma unroll
    for (int k = 0; k < 4; ++k) {
        const int ts = t - 3 + k;
        if (ts >= 0) {
            float4 v = *(const float4*)(base + (size_t)ts * ldxz);
            float wk0 = (&w0.x)[k], wk1 = (&w1.x)[k], wk2 = (&w2.x)[k], wk3 = (&w3.x)[k];
            acc.x = fmaf(v.x, wk0, acc.x);
            acc.y = fmaf(v.y, wk1, acc.y);
            acc.z = fmaf(v.z, wk2, acc.z);
            acc.w = fmaf(v.w, wk3, acc.w);
        }
    }
    // SiLU
    acc.x = acc.x / (1.f + __expf(-acc.x));
    acc.y = acc.y / (1.f + __expf(-acc.y));
    acc.z = acc.z / (1.f + __expf(-acc.z));
    acc.w = acc.w / (1.f + __expf(-acc.w));

    *(float4*)(xc + ((size_t)b * L + t) * dinner + d4) = acc;
}

// ---------------------------------------------------------------------------
// Fused selective scan.
// Thread = (b, d, s); s = lane&15 within a 16-lane group (same wave).
// Fuses: softplus(dt_raw + dtb), dA = exp(dt*A), dBx = dt*B*xc, the recurrence,
// the d_state reduction, D-skip, and the SiLU(z) gate.
// Writes gated y IN PLACE over dt_raw (safe: 16 lanes of one wave share d;
// loads at step t precede the lane-0 store in lockstep program order).
// ---------------------------------------------------------------------------
__global__ __launch_bounds__(256)
void scan_fused(const float* __restrict__ dtraw,  // (B,L,dinner)
                const float* __restrict__ xc,     // (B,L,dinner)
                const float* __restrict__ dbl,    // (B,L,96): [0:64|64:80|80:96]
                const float* __restrict__ xz,     // (B,L,2*dinner), z = cols dinner..
                const float* __restrict__ dtb,    // (dinner)
                const float* __restrict__ alog,   // (dinner,16)
                const float* __restrict__ Dp,     // (dinner)
                float* __restrict__ yg,           // (B,L,dinner) out
                int Bsz, int L, int dinner)
{
    const int g = blockIdx.x * blockDim.x + threadIdx.x;
    const int s = g & 15;
    const int d = (g >> 4) % dinner;
    const int b = g / (16 * dinner);
    if (b >= Bsz) return;

    const float Aval = -__expf(alog[(size_t)d * 16 + s]);
    const float bias = dtb[d];
    const float Dval = Dp[d];

    const float* dt_p = dtraw + (size_t)b * L * dinner + d;
    const float* xc_p = xc    + (size_t)b * L * dinner + d;
    const float* bl_p = dbl   + (size_t)b * L * 96;
    const float* z_p  = xz    + (size_t)b * L * (2 * dinner) + dinner + d;
    float*       y_p  = yg    + (size_t)b * L * dinner + d;

    float h = 0.f;
    for (int t = 0; t < L; ++t) {
        const float dtv = dt_p[(size_t)t * dinner];
        const float xcv = xc_p[(size_t)t * dinner];
        const float Bv  = bl_p[t * 96 + 64 + s];
        const float Cv  = bl_p[t * 96 + 80 + s];
        const float zv  = z_p[(size_t)t * 2 * dinner];

        float x  = dtv + bias;
        float sp = (x > 20.f) ? x : __logf(1.f + __expf(x));   // softplus
        float dA = __expf(sp * Aval);
        h = fmaf(dA, h, sp * Bv * xcv);

        float y = h * Cv;
        y += __shfl_xor(y, 1, 16);
        y += __shfl_xor(y, 2, 16);
        y += __shfl_xor(y, 4, 16);
        y += __shfl_xor(y, 8, 16);

        if (s == 0) {
            y = fmaf(xcv, Dval, y);
            const float sig = 1.f / (1.f + __expf(-zv));
            y_p[(size_t)t * dinner] = y * (zv * sig);
        }
    }
}

// ---------------------------------------------------------------------------
extern "C" void kernel_launch(void* const* d_in, const int* in_sizes, int n_in,
                              void* d_out, int out_size, void* d_ws, size_t ws_size,
                              hipStream_t stream)
{
    const float* x    = (const float*)d_in[0];
    const float* inw  = (const float*)d_in[1];
    const float* cw   = (const float*)d_in[2];
    const float* cb   = (const float*)d_in[3];
    const float* xw   = (const float*)d_in[4];
    const float* dtw  = (const float*)d_in[5];
    const float* dtb  = (const float*)d_in[6];
    const float* alog = (const float*)d_in[7];
    const float* Dp   = (const float*)d_in[8];
    const float* ow   = (const float*)d_in[9];
    float* out = (float*)d_out;

    const int Bsz = 2, L = 1024, dmodel = 1024, dinner = 2048;
    const int BL = Bsz * L;            // 2048 rows for every GEMM
    const int dbl_w = 96;              // dt_rank(64) + 2*d_state(32)

    float* ws    = (float*)d_ws;
    float* xzb   = ws;                                  // BL * 4096
    float* xcb   = xzb   + (size_t)BL * 2 * dinner;     // BL * 2048
    float* dblb  = xcb   + (size_t)BL * dinner;         // BL * 96
    float* dtrb  = dblb  + (size_t)BL * dbl_w;          // BL * 2048 (also y_gated)
    float* x1b   = dtrb  + (size_t)BL * dinner;         // BL * 1024 (layer-1 out)

    const float* cur = x;
    for (int l = 0; l < 2; ++l) {
        const float* inw_l  = inw  + (size_t)l * 2 * dinner * dmodel;
        const float* cw_l   = cw   + (size_t)l * dinner * 4;
        const float* cb_l   = cb   + (size_t)l * dinner;
        const float* xw_l   = xw   + (size_t)l * dbl_w * dinner;
        const float* dtw_l  = dtw  + (size_t)l * dinner * 64;
        const float* dtb_l  = dtb  + (size_t)l * dinner;
        const float* alog_l = alog + (size_t)l * dinner * 16;
        const float* Dp_l   = Dp   + (size_t)l * dinner;
        const float* ow_l   = ow   + (size_t)l * dmodel * dinner;
        float* outbuf = (l == 0) ? x1b : out;

        // 1) xz = cur @ in_w^T            (2048 x 4096, K=1024)
        gemm_nt<<<dim3(2 * dinner / 128, BL / 128), 256, 0, stream>>>(
            cur, inw_l, xzb, BL, 2 * dinner, dmodel, dmodel, dmodel, 2 * dinner);

        // 2) xc = silu(causal_conv(xr) + cb)
        conv_silu<<<(BL * dinner / 4) / 256, 256, 0, stream>>>(
            xzb, cw_l, cb_l, xcb, Bsz, L, dinner);

        // 3) dbl = xc @ xw^T              (2048 x 96, K=2048)
        gemm_nt<<<dim3(1, BL / 128), 256, 0, stream>>>(
            xcb, xw_l, dblb, BL, dbl_w, dinner, dinner, dinner, dbl_w);

        // 4) dt_raw = dbl[:, :64] @ dtw^T (2048 x 2048, K=64)
        gemm_nt<<<dim3(dinner / 128, BL / 128), 256, 0, stream>>>(
            dblb, dtw_l, dtrb, BL, dinner, 64, dbl_w, 64, dinner);

        // 5) fused scan (+softplus, gate, D-skip); writes y_gated over dt_raw
        scan_fused<<<(Bsz * dinner * 16) / 256, 256, 0, stream>>>(
            dtrb, xcb, dblb, xzb, dtb_l, alog_l, Dp_l, dtrb, Bsz, L, dinner);

        // 6) out = y_gated @ ow^T         (2048 x 1024, K=2048)
        gemm_nt<<<dim3(dmodel / 128, BL / 128), 256, 0, stream>>>(
            dtrb, ow_l, outbuf, BL, dmodel, dinner, dinner, dinner, dmodel);

        cur = outbuf;
    }
}

// Round 2
// 1962.226 us; speedup vs baseline: 1.6296x; 1.6296x over previous
//
#include <hip/hip_runtime.h>
#include <cmath>

// ---------------------------------------------------------------------------
// Generic tiled NT GEMM: C[M,N] = A[M,K] * B[N,K]^T
// ---------------------------------------------------------------------------
__global__ __launch_bounds__(256)
void gemm_nt(const float* __restrict__ A, const float* __restrict__ B,
             float* __restrict__ C, int M, int N, int K,
             int lda, int ldb, int ldc)
{
    __shared__ float As[8][132];
    __shared__ float Bs[8][132];

    const int tid  = threadIdx.x;
    const int row0 = blockIdx.y * 128;
    const int col0 = blockIdx.x * 128;

    const int lr = tid >> 1;
    const int lk = (tid & 1) * 4;

    const int ty = tid >> 4;
    const int tx = tid & 15;

    float acc[8][8];
    #pragma unroll
    for (int i = 0; i < 8; ++i)
        #pragma unroll
        for (int j = 0; j < 8; ++j) acc[i][j] = 0.f;

    for (int k0 = 0; k0 < K; k0 += 8) {
        float4 av = *(const float4*)(A + (size_t)(row0 + lr) * lda + k0 + lk);
        float4 bv = make_float4(0.f, 0.f, 0.f, 0.f);
        const int brow = col0 + lr;
        if (brow < N)
            bv = *(const float4*)(B + (size_t)brow * ldb + k0 + lk);

        __syncthreads();
        As[lk + 0][lr] = av.x; As[lk + 1][lr] = av.y;
        As[lk + 2][lr] = av.z; As[lk + 3][lr] = av.w;
        Bs[lk + 0][lr] = bv.x; Bs[lk + 1][lr] = bv.y;
        Bs[lk + 2][lr] = bv.z; Bs[lk + 3][lr] = bv.w;
        __syncthreads();

        #pragma unroll
        for (int k = 0; k < 8; ++k) {
            float4 a0 = *(const float4*)&As[k][ty * 8];
            float4 a1 = *(const float4*)&As[k][ty * 8 + 4];
            float4 b0 = *(const float4*)&Bs[k][tx * 8];
            float4 b1 = *(const float4*)&Bs[k][tx * 8 + 4];
            float a[8] = {a0.x, a0.y, a0.z, a0.w, a1.x, a1.y, a1.z, a1.w};
            float b[8] = {b0.x, b0.y, b0.z, b0.w, b1.x, b1.y, b1.z, b1.w};
            #pragma unroll
            for (int i = 0; i < 8; ++i)
                #pragma unroll
                for (int j = 0; j < 8; ++j)
                    acc[i][j] = fmaf(a[i], b[j], acc[i][j]);
        }
    }

    #pragma unroll
    for (int i = 0; i < 8; ++i) {
        const int r = row0 + ty * 8 + i;
        #pragma unroll
        for (int j = 0; j < 8; ++j) {
            const int c = col0 + tx * 8 + j;
            if (c < N) C[(size_t)r * ldc + c] = acc[i][j];
        }
    }
}

// ---------------------------------------------------------------------------
// Causal depthwise conv1d (width 4) + bias + SiLU.
// ---------------------------------------------------------------------------
__global__ __launch_bounds__(256)
void conv_silu(const float* __restrict__ xz, const float* __restrict__ cw,
               const float* __restrict__ cb, float* __restrict__ xc,
               int Bsz, int L, int dinner)
{
    const int nv = dinner / 4;
    const int g  = blockIdx.x * blockDim.x + threadIdx.x;
    const int d4 = (g % nv) * 4;
    const int t  = (g / nv) % L;
    const int b  = g / (nv * L);
    if (b >= Bsz) return;

    const int ldxz = 2 * dinner;
    float4 w0 = *(const float4*)(cw + (size_t)(d4 + 0) * 4);
    float4 w1 = *(const float4*)(cw + (size_t)(d4 + 1) * 4);
    float4 w2 = *(const float4*)(cw + (size_t)(d4 + 2) * 4);
    float4 w3 = *(const float4*)(cw + (size_t)(d4 + 3) * 4);
    float4 acc = *(const float4*)(cb + d4);

    const float* base = xz + (size_t)b * L * ldxz + d4;
    #pragma unroll
    for (int k = 0; k < 4; ++k) {
        const int ts = t - 3 + k;
        if (ts >= 0) {
            float4 v = *(const float4*)(base + (size_t)ts * ldxz);
            float wk0 = (&w0.x)[k], wk1 = (&w1.x)[k], wk2 = (&w2.x)[k], wk3 = (&w3.x)[k];
            acc.x = fmaf(v.x, wk0, acc.x);
            acc.y = fmaf(v.y, wk1, acc.y);
            acc.z = fmaf(v.z, wk2, acc.z);
            acc.w = fmaf(v.w, wk3, acc.w);
        }
    }
    acc.x = acc.x / (1.f + __expf(-acc.x));
    acc.y = acc.y / (1.f + __expf(-acc.y));
    acc.z = acc.z / (1.f + __expf(-acc.z));
    acc.w = acc.w / (1.f + __expf(-acc.w));

    *(float4*)(xc + ((size_t)b * L + t) * dinner + d4) = acc;
}

// ---------------------------------------------------------------------------
// Chunked scan, pass 1: each (b, chunk, d, s) thread scans its chunk from
// h=0, emitting the chunk-final state hend and (s==0) the softplus-sum S.
// Chunk transition over the chunk is exactly exp(Aval * S).
// ---------------------------------------------------------------------------
__global__ __launch_bounds__(256)
void scan_part1(const float* __restrict__ dtraw,  // (B,L,dinner)
                const float* __restrict__ xc,     // (B,L,dinner)
                const float* __restrict__ dbl,    // (B,L,96)
                const float* __restrict__ dtb,    // (dinner)
                const float* __restrict__ alog,   // (dinner,16)
                float* __restrict__ hend,         // (B,NC,dinner,16)
                float* __restrict__ Ssum,         // (B,NC,dinner)
                int Bsz, int L, int dinner, int NC, int CL)
{
    const int g = blockIdx.x * blockDim.x + threadIdx.x;
    const int s = g & 15;
    const int d = (g >> 4) % dinner;
    const int c = (g / (16 * dinner)) % NC;
    const int b = g / (16 * dinner * NC);
    if (b >= Bsz) return;

    const float Aval = -__expf(alog[(size_t)d * 16 + s]);
    const float bias = dtb[d];

    const int t0 = c * CL;
    const float* dt_p = dtraw + ((size_t)b * L + t0) * dinner + d;
    const float* xc_p = xc    + ((size_t)b * L + t0) * dinner + d;
    const float* bl_p = dbl   + ((size_t)b * L + t0) * 96;

    float h = 0.f;
    float S = 0.f;
    for (int t = 0; t < CL; ++t) {
        const float dtv = dt_p[(size_t)t * dinner];
        const float xcv = xc_p[(size_t)t * dinner];
        const float Bv  = bl_p[t * 96 + 64 + s];

        float xv = dtv + bias;
        float sp = (xv > 20.f) ? xv : __logf(1.f + __expf(xv));
        S += sp;
        float dA = __expf(sp * Aval);
        h = fmaf(dA, h, sp * Bv * xcv);
    }

    hend[(((size_t)b * NC + c) * dinner + d) * 16 + s] = h;
    if (s == 0) Ssum[((size_t)b * NC + c) * dinner + d] = S;
}

// ---------------------------------------------------------------------------
// Chunked scan, pass 2: compose entry state from previous chunk summaries,
// then scan the chunk computing y, d_state reduce, D-skip, SiLU(z) gate.
// Writes gated y IN PLACE over dt_raw (safe within the lockstep 16-lane group).
// ---------------------------------------------------------------------------
__global__ __launch_bounds__(256)
void scan_part2(const float* __restrict__ dtraw,
                const float* __restrict__ xc,
                const float* __restrict__ dbl,
                const float* __restrict__ xz,     // z = cols dinner..2*dinner
                const float* __restrict__ dtb,
                const float* __restrict__ alog,
                const float* __restrict__ Dp,
                const float* __restrict__ hend,
                const float* __restrict__ Ssum,
                float* __restrict__ yg,
                int Bsz, int L, int dinner, int NC, int CL)
{
    const int g = blockIdx.x * blockDim.x + threadIdx.x;
    const int s = g & 15;
    const int d = (g >> 4) % dinner;
    const int c = (g / (16 * dinner)) % NC;
    const int b = g / (16 * dinner * NC);
    if (b >= Bsz) return;

    const float Aval = -__expf(alog[(size_t)d * 16 + s]);
    const float bias = dtb[d];
    const float Dval = Dp[d];

    // entry state from previous chunks
    float h = 0.f;
    for (int cp = 0; cp < c; ++cp) {
        const float Sv = Ssum[((size_t)b * NC + cp) * dinner + d];
        const float he = hend[(((size_t)b * NC + cp) * dinner + d) * 16 + s];
        h = fmaf(__expf(Aval * Sv), h, he);
    }

    const int t0 = c * CL;
    const float* dt_p = dtraw + ((size_t)b * L + t0) * dinner + d;
    const float* xc_p = xc    + ((size_t)b * L + t0) * dinner + d;
    const float* bl_p = dbl   + ((size_t)b * L + t0) * 96;
    const float* z_p  = xz    + ((size_t)b * L + t0) * (2 * dinner) + dinner + d;
    float*       y_p  = yg    + ((size_t)b * L + t0) * dinner + d;

    for (int t = 0; t < CL; ++t) {
        const float dtv = dt_p[(size_t)t * dinner];
        const float xcv = xc_p[(size_t)t * dinner];
        const float Bv  = bl_p[t * 96 + 64 + s];
        const float Cv  = bl_p[t * 96 + 80 + s];
        const float zv  = z_p[(size_t)t * 2 * dinner];

        float xv = dtv + bias;
        float sp = (xv > 20.f) ? xv : __logf(1.f + __expf(xv));
        float dA = __expf(sp * Aval);
        h = fmaf(dA, h, sp * Bv * xcv);

        float y = h * Cv;
        y += __shfl_xor(y, 1, 16);
        y += __shfl_xor(y, 2, 16);
        y += __shfl_xor(y, 4, 16);
        y += __shfl_xor(y, 8, 16);

        if (s == 0) {
            y = fmaf(xcv, Dval, y);
            const float sig = 1.f / (1.f + __expf(-zv));
            y_p[(size_t)t * dinner] = y * (zv * sig);
        }
    }
}

// ---------------------------------------------------------------------------
extern "C" void kernel_launch(void* const* d_in, const int* in_sizes, int n_in,
                              void* d_out, int out_size, void* d_ws, size_t ws_size,
                              hipStream_t stream)
{
    const float* x    = (const float*)d_in[0];
    const float* inw  = (const float*)d_in[1];
    const float* cw   = (const float*)d_in[2];
    const float* cb   = (const float*)d_in[3];
    const float* xw   = (const float*)d_in[4];
    const float* dtw  = (const float*)d_in[5];
    const float* dtb  = (const float*)d_in[6];
    const float* alog = (const float*)d_in[7];
    const float* Dp   = (const float*)d_in[8];
    const float* ow   = (const float*)d_in[9];
    float* out = (float*)d_out;

    const int Bsz = 2, L = 1024, dmodel = 1024, dinner = 2048;
    const int BL = Bsz * L;
    const int dbl_w = 96;
    const int NC = 8, CL = L / NC;   // 8 chunks of 128

    float* ws    = (float*)d_ws;
    float* xzb   = ws;                                  // BL * 4096
    float* xcb   = xzb   + (size_t)BL * 2 * dinner;     // BL * 2048
    float* dblb  = xcb   + (size_t)BL * dinner;         // BL * 96
    float* dtrb  = dblb  + (size_t)BL * dbl_w;          // BL * 2048 (also y_gated)
    float* x1b   = dtrb  + (size_t)BL * dinner;         // BL * 1024
    float* hendb = x1b   + (size_t)BL * dmodel;         // B*NC*dinner*16
    float* ssumb = hendb + (size_t)Bsz * NC * dinner * 16;  // B*NC*dinner

    const int scan_threads = Bsz * NC * dinner * 16;    // 524288

    const float* cur = x;
    for (int l = 0; l < 2; ++l) {
        const float* inw_l  = inw  + (size_t)l * 2 * dinner * dmodel;
        const float* cw_l   = cw   + (size_t)l * dinner * 4;
        const float* cb_l   = cb   + (size_t)l * dinner;
        const float* xw_l   = xw   + (size_t)l * dbl_w * dinner;
        const float* dtw_l  = dtw  + (size_t)l * dinner * 64;
        const float* dtb_l  = dtb  + (size_t)l * dinner;
        const float* alog_l = alog + (size_t)l * dinner * 16;
        const float* Dp_l   = Dp   + (size_t)l * dinner;
        const float* ow_l   = ow   + (size_t)l * dmodel * dinner;
        float* outbuf = (l == 0) ? x1b : out;

        // 1) xz = cur @ in_w^T            (2048 x 4096, K=1024)
        gemm_nt<<<dim3(2 * dinner / 128, BL / 128), 256, 0, stream>>>(
            cur, inw_l, xzb, BL, 2 * dinner, dmodel, dmodel, dmodel, 2 * dinner);

        // 2) xc = silu(causal_conv(xr) + cb)
        conv_silu<<<(BL * dinner / 4) / 256, 256, 0, stream>>>(
            xzb, cw_l, cb_l, xcb, Bsz, L, dinner);

        // 3) dbl = xc @ xw^T              (2048 x 96, K=2048)
        gemm_nt<<<dim3(1, BL / 128), 256, 0, stream>>>(
            xcb, xw_l, dblb, BL, dbl_w, dinner, dinner, dinner, dbl_w);

        // 4) dt_raw = dbl[:, :64] @ dtw^T (2048 x 2048, K=64)
        gemm_nt<<<dim3(dinner / 128, BL / 128), 256, 0, stream>>>(
            dblb, dtw_l, dtrb, BL, dinner, 64, dbl_w, 64, dinner);

        // 5a) chunked scan pass 1: local scans + chunk summaries
        scan_part1<<<scan_threads / 256, 256, 0, stream>>>(
            dtrb, xcb, dblb, dtb_l, alog_l, hendb, ssumb,
            Bsz, L, dinner, NC, CL);

        // 5b) chunked scan pass 2: compose entry states, full scan + gate
        scan_part2<<<scan_threads / 256, 256, 0, stream>>>(
            dtrb, xcb, dblb, xzb, dtb_l, alog_l, Dp_l, hendb, ssumb, dtrb,
            Bsz, L, dinner, NC, CL);

        // 6) out = y_gated @ ow^T         (2048 x 1024, K=2048)
        gemm_nt<<<dim3(dmodel / 128, BL / 128), 256, 0, stream>>>(
            dtrb, ow_l, outbuf, BL, dmodel, dinner, dinner, dinner, dmodel);

        cur = outbuf;
    }
}

// Round 4
// 652.538 us; speedup vs baseline: 4.9003x; 3.0071x over previous
//
#include <hip/hip_runtime.h>
#include <hip/hip_bf16.h>
#include <cmath>

typedef __bf16 bf16x8_t __attribute__((ext_vector_type(8)));
typedef float  f32x4_t  __attribute__((ext_vector_type(4)));
using bf16 = __hip_bfloat16;

// ---------------------------------------------------------------------------
// f32 -> bf16 cast, 8 elems/thread
// ---------------------------------------------------------------------------
__global__ __launch_bounds__(256)
void cast_f32_bf16(const float* __restrict__ src, bf16* __restrict__ dst, int n8)
{
    const int i = blockIdx.x * blockDim.x + threadIdx.x;
    if (i >= n8) return;
    const float4* s = (const float4*)(src + (size_t)i * 8);
    float4 a = s[0], b = s[1];
    bf16 o[8];
    o[0] = __float2bfloat16(a.x); o[1] = __float2bfloat16(a.y);
    o[2] = __float2bfloat16(a.z); o[3] = __float2bfloat16(a.w);
    o[4] = __float2bfloat16(b.x); o[5] = __float2bfloat16(b.y);
    o[6] = __float2bfloat16(b.z); o[7] = __float2bfloat16(b.w);
    *(int4*)(dst + (size_t)i * 8) = *(int4*)o;
}

// ---------------------------------------------------------------------------
// bf16 MFMA NT GEMM: C[M,N] = A[M,K] * B[N,K]^T, fp32 accumulate.
// BM=BN=128, BK=32, 256 threads = 4 waves, each wave a 64x64 sub-tile
// (4x4 fragments of 16x16x32). Staging: thread -> (row tid>>1, 16-elem half
// (tid&1)*16), loaded as TWO int4 (16 bf16 = 32 bytes). LDS rows padded to
// 40 bf16. MODE: 0 = f32 store, 1 = bf16 store, 2 = both. N bounds-checked.
// ---------------------------------------------------------------------------
template<int MODE>
__global__ __launch_bounds__(256)
void gemm_bf16(const bf16* __restrict__ A, const bf16* __restrict__ B,
               float* __restrict__ Cf, bf16* __restrict__ Cb,
               int M, int N, int K, int lda, int ldb, int ldc)
{
    __shared__ __align__(16) bf16 At[128][40];
    __shared__ __align__(16) bf16 Bt[128][40];

    const int tid  = threadIdx.x;
    const int lane = tid & 63;
    const int wid  = tid >> 6;       // wave 0..3
    const int wr   = wid >> 1;       // wave row 0..1 (64 rows each)
    const int wc   = wid & 1;        // wave col 0..1
    const int fr   = lane & 15;      // fragment row/col
    const int fq   = lane >> 4;      // k-octet / acc row quad

    const int row0 = blockIdx.y * 128;
    const int col0 = blockIdx.x * 128;

    const int srow  = tid >> 1;
    const int shalf = tid & 1;

    const bf16* aptr = A + (size_t)(row0 + srow) * lda + shalf * 16;
    int bRow = col0 + srow; if (bRow >= N) bRow = N - 1;   // clamp; dup cols never stored
    const bf16* bptr = B + (size_t)bRow * ldb + shalf * 16;

    f32x4_t acc[4][4];
    #pragma unroll
    for (int m = 0; m < 4; ++m)
        #pragma unroll
        for (int n = 0; n < 4; ++n)
            acc[m][n] = f32x4_t{0.f, 0.f, 0.f, 0.f};

    int4 ra0 = *(const int4*)(aptr);
    int4 ra1 = *(const int4*)(aptr + 8);
    int4 rb0 = *(const int4*)(bptr);
    int4 rb1 = *(const int4*)(bptr + 8);

    for (int k0 = 0; k0 < K; k0 += 32) {
        __syncthreads();                          // readers of prev tile done
        *(int4*)&At[srow][shalf * 16 + 0] = ra0;
        *(int4*)&At[srow][shalf * 16 + 8] = ra1;
        *(int4*)&Bt[srow][shalf * 16 + 0] = rb0;
        *(int4*)&Bt[srow][shalf * 16 + 8] = rb1;
        __syncthreads();
        if (k0 + 32 < K) {                        // prefetch next tile
            ra0 = *(const int4*)(aptr + k0 + 32);
            ra1 = *(const int4*)(aptr + k0 + 40);
            rb0 = *(const int4*)(bptr + k0 + 32);
            rb1 = *(const int4*)(bptr + k0 + 40);
        }
        bf16x8_t af[4], bg[4];
        #pragma unroll
        for (int m = 0; m < 4; ++m)
            af[m] = *(const bf16x8_t*)&At[wr * 64 + m * 16 + fr][fq * 8];
        #pragma unroll
        for (int n = 0; n < 4; ++n)
            bg[n] = *(const bf16x8_t*)&Bt[wc * 64 + n * 16 + fr][fq * 8];
        #pragma unroll
        for (int m = 0; m < 4; ++m)
            #pragma unroll
            for (int n = 0; n < 4; ++n)
                acc[m][n] = __builtin_amdgcn_mfma_f32_16x16x32_bf16(
                    af[m], bg[n], acc[m][n], 0, 0, 0);
    }

    // C/D layout: col = lane&15, row = (lane>>4)*4 + reg
    #pragma unroll
    for (int m = 0; m < 4; ++m) {
        #pragma unroll
        for (int n = 0; n < 4; ++n) {
            const int c = col0 + wc * 64 + n * 16 + fr;
            if (c < N) {
                #pragma unroll
                for (int r = 0; r < 4; ++r) {
                    const int rr = row0 + wr * 64 + m * 16 + fq * 4 + r;
                    if (MODE != 1) Cf[(size_t)rr * ldc + c] = acc[m][n][r];
                    if (MODE != 0) Cb[(size_t)rr * ldc + c] = __float2bfloat16(acc[m][n][r]);
                }
            }
        }
    }
}

// ---------------------------------------------------------------------------
// Causal depthwise conv1d (width 4) + bias + SiLU. Reads fp32 xr half of xz,
// writes bf16 xc.
// ---------------------------------------------------------------------------
__global__ __launch_bounds__(256)
void conv_silu(const float* __restrict__ xz, const float* __restrict__ cw,
               const float* __restrict__ cb, bf16* __restrict__ xc,
               int Bsz, int L, int dinner)
{
    const int nv = dinner / 4;
    const int g  = blockIdx.x * blockDim.x + threadIdx.x;
    const int d4 = (g % nv) * 4;
    const int t  = (g / nv) % L;
    const int b  = g / (nv * L);
    if (b >= Bsz) return;

    const int ldxz = 2 * dinner;
    float4 w0 = *(const float4*)(cw + (size_t)(d4 + 0) * 4);
    float4 w1 = *(const float4*)(cw + (size_t)(d4 + 1) * 4);
    float4 w2 = *(const float4*)(cw + (size_t)(d4 + 2) * 4);
    float4 w3 = *(const float4*)(cw + (size_t)(d4 + 3) * 4);
    float4 acc = *(const float4*)(cb + d4);

    const float* base = xz + (size_t)b * L * ldxz + d4;
    #pragma unroll
    for (int k = 0; k < 4; ++k) {
        const int ts = t - 3 + k;
        if (ts >= 0) {
            float4 v = *(const float4*)(base + (size_t)ts * ldxz);
            acc.x = fmaf(v.x, (&w0.x)[k], acc.x);
            acc.y = fmaf(v.y, (&w1.x)[k], acc.y);
            acc.z = fmaf(v.z, (&w2.x)[k], acc.z);
            acc.w = fmaf(v.w, (&w3.x)[k], acc.w);
        }
    }
    acc.x = acc.x / (1.f + __expf(-acc.x));
    acc.y = acc.y / (1.f + __expf(-acc.y));
    acc.z = acc.z / (1.f + __expf(-acc.z));
    acc.w = acc.w / (1.f + __expf(-acc.w));

    bf16 o[4];
    o[0] = __float2bfloat16(acc.x); o[1] = __float2bfloat16(acc.y);
    o[2] = __float2bfloat16(acc.z); o[3] = __float2bfloat16(acc.w);
    *(int2*)(xc + ((size_t)b * L + t) * dinner + d4) = *(int2*)o;
}

// ---------------------------------------------------------------------------
// Chunked scan pass 1: per-(b,chunk,d,s) local scan from h=0; emits chunk-final
// state hend and (s==0) the softplus-sum S (chunk transition = exp(A*S)).
// ---------------------------------------------------------------------------
__global__ __launch_bounds__(256)
void scan_part1(const bf16* __restrict__ dtraw,   // (B,L,dinner) bf16
                const bf16* __restrict__ xc,      // (B,L,dinner) bf16
                const float* __restrict__ dbl,    // (B,L,96)
                const float* __restrict__ dtb,
                const float* __restrict__ alog,   // (dinner,16)
                float* __restrict__ hend,         // (B,NC,dinner,16)
                float* __restrict__ Ssum,         // (B,NC,dinner)
                int Bsz, int L, int dinner, int NC, int CL)
{
    const int g = blockIdx.x * blockDim.x + threadIdx.x;
    const int s = g & 15;
    const int d = (g >> 4) % dinner;
    const int c = (g / (16 * dinner)) % NC;
    const int b = g / (16 * dinner * NC);
    if (b >= Bsz) return;

    const float Aval = -__expf(alog[(size_t)d * 16 + s]);
    const float bias = dtb[d];

    const int t0 = c * CL;
    const bf16*  dt_p = dtraw + ((size_t)b * L + t0) * dinner + d;
    const bf16*  xc_p = xc    + ((size_t)b * L + t0) * dinner + d;
    const float* bl_p = dbl   + ((size_t)b * L + t0) * 96;

    float h = 0.f, S = 0.f;
    for (int t = 0; t < CL; ++t) {
        const float dtv = __bfloat162float(dt_p[(size_t)t * dinner]);
        const float xcv = __bfloat162float(xc_p[(size_t)t * dinner]);
        const float Bv  = bl_p[t * 96 + 64 + s];

        float xv = dtv + bias;
        float sp = (xv > 20.f) ? xv : __logf(1.f + __expf(xv));
        S += sp;
        h = fmaf(__expf(sp * Aval), h, sp * Bv * xcv);
    }

    hend[(((size_t)b * NC + c) * dinner + d) * 16 + s] = h;
    if (s == 0) Ssum[((size_t)b * NC + c) * dinner + d] = S;
}

// ---------------------------------------------------------------------------
// Chunked scan pass 2: compose entry state, re-scan chunk, d_state reduce,
// D-skip, SiLU(z) gate. Writes bf16 gated y IN PLACE over dt_raw (dty):
// all 16 lockstep lanes load dty[t] before lane 0's store of the same addr.
// ---------------------------------------------------------------------------
__global__ __launch_bounds__(256)
void scan_part2(bf16* dty,                        // (B,L,dinner): dt_raw in, y out
                const bf16* __restrict__ xc,
                const float* __restrict__ dbl,
                const float* __restrict__ xz,     // z = cols dinner..2*dinner (f32)
                const float* __restrict__ dtb,
                const float* __restrict__ alog,
                const float* __restrict__ Dp,
                const float* __restrict__ hend,
                const float* __restrict__ Ssum,
                int Bsz, int L, int dinner, int NC, int CL)
{
    const int g = blockIdx.x * blockDim.x + threadIdx.x;
    const int s = g & 15;
    const int d = (g >> 4) % dinner;
    const int c = (g / (16 * dinner)) % NC;
    const int b = g / (16 * dinner * NC);
    if (b >= Bsz) return;

    const float Aval = -__expf(alog[(size_t)d * 16 + s]);
    const float bias = dtb[d];
    const float Dval = Dp[d];

    float h = 0.f;
    for (int cp = 0; cp < c; ++cp) {
        const float Sv = Ssum[((size_t)b * NC + cp) * dinner + d];
        const float he = hend[(((size_t)b * NC + cp) * dinner + d) * 16 + s];
        h = fmaf(__expf(Aval * Sv), h, he);
    }

    const int t0 = c * CL;
    bf16*        dt_p = dty + ((size_t)b * L + t0) * dinner + d;
    const bf16*  xc_p = xc  + ((size_t)b * L + t0) * dinner + d;
    const float* bl_p = dbl + ((size_t)b * L + t0) * 96;
    const float* z_p  = xz  + ((size_t)b * L + t0) * (2 * dinner) + dinner + d;

    for (int t = 0; t < CL; ++t) {
        const float dtv = __bfloat162float(dt_p[(size_t)t * dinner]);
        const float xcv = __bfloat162float(xc_p[(size_t)t * dinner]);
        const float Bv  = bl_p[t * 96 + 64 + s];
        const float Cv  = bl_p[t * 96 + 80 + s];
        const float zv  = z_p[(size_t)t * 2 * dinner];

        float xv = dtv + bias;
        float sp = (xv > 20.f) ? xv : __logf(1.f + __expf(xv));
        h = fmaf(__expf(sp * Aval), h, sp * Bv * xcv);

        float y = h * Cv;
        y += __shfl_xor(y, 1, 16);
        y += __shfl_xor(y, 2, 16);
        y += __shfl_xor(y, 4, 16);
        y += __shfl_xor(y, 8, 16);

        if (s == 0) {
            y = fmaf(xcv, Dval, y);
            const float sig = 1.f / (1.f + __expf(-zv));
            dt_p[(size_t)t * dinner] = __float2bfloat16(y * (zv * sig));
        }
    }
}

// ---------------------------------------------------------------------------
extern "C" void kernel_launch(void* const* d_in, const int* in_sizes, int n_in,
                              void* d_out, int out_size, void* d_ws, size_t ws_size,
                              hipStream_t stream)
{
    const float* x    = (const float*)d_in[0];
    const float* inw  = (const float*)d_in[1];
    const float* cw   = (const float*)d_in[2];
    const float* cb   = (const float*)d_in[3];
    const float* xw   = (const float*)d_in[4];
    const float* dtw  = (const float*)d_in[5];
    const float* dtb  = (const float*)d_in[6];
    const float* alog = (const float*)d_in[7];
    const float* Dp   = (const float*)d_in[8];
    const float* ow   = (const float*)d_in[9];
    float* out = (float*)d_out;

    const int Bsz = 2, L = 1024, dmodel = 1024, dinner = 2048;
    const int BL = Bsz * L;            // 2048
    const int NC = 8, CL = L / NC;     // 8 chunks of 128

    // --- workspace layout ---------------------------------------------------
    char* p = (char*)d_ws;
    auto alloc = [&](size_t bytes) { char* r = p; p += (bytes + 63) & ~size_t(63); return r; };
    bf16*  wb_in  = (bf16*) alloc((size_t)2 * dinner * dmodel * 2);
    bf16*  wb_x   = (bf16*) alloc((size_t)96 * dinner * 2);
    bf16*  wb_dt  = (bf16*) alloc((size_t)dinner * 64 * 2);
    bf16*  wb_ow  = (bf16*) alloc((size_t)dmodel * dinner * 2);
    bf16*  curb   = (bf16*) alloc((size_t)BL * dmodel * 2);
    float* xzb    = (float*)alloc((size_t)BL * 2 * dinner * 4);
    bf16*  xcb16  = (bf16*) alloc((size_t)BL * dinner * 2);
    float* dblb   = (float*)alloc((size_t)BL * 96 * 4);
    bf16*  dblb16 = (bf16*) alloc((size_t)BL * 96 * 2);
    bf16*  dtrb16 = (bf16*) alloc((size_t)BL * dinner * 2);
    float* hendb  = (float*)alloc((size_t)Bsz * NC * dinner * 16 * 4);
    float* ssumb  = (float*)alloc((size_t)Bsz * NC * dinner * 4);

    const int scan_blocks = (Bsz * NC * dinner * 16) / 256;   // 2048

    cast_f32_bf16<<<(BL * dmodel / 8) / 256, 256, 0, stream>>>(x, curb, BL * dmodel / 8);

    for (int l = 0; l < 2; ++l) {
        const float* inw_l  = inw  + (size_t)l * 2 * dinner * dmodel;
        const float* cw_l   = cw   + (size_t)l * dinner * 4;
        const float* cb_l   = cb   + (size_t)l * dinner;
        const float* xw_l   = xw   + (size_t)l * 96 * dinner;
        const float* dtw_l  = dtw  + (size_t)l * dinner * 64;
        const float* dtb_l  = dtb  + (size_t)l * dinner;
        const float* alog_l = alog + (size_t)l * dinner * 16;
        const float* Dp_l   = Dp   + (size_t)l * dinner;
        const float* ow_l   = ow   + (size_t)l * dmodel * dinner;

        cast_f32_bf16<<<(2 * dinner * dmodel / 8) / 256, 256, 0, stream>>>(
            inw_l, wb_in, 2 * dinner * dmodel / 8);
        cast_f32_bf16<<<(96 * dinner / 8) / 256, 256, 0, stream>>>(
            xw_l, wb_x, 96 * dinner / 8);
        cast_f32_bf16<<<(dinner * 64 / 8) / 256, 256, 0, stream>>>(
            dtw_l, wb_dt, dinner * 64 / 8);
        cast_f32_bf16<<<(dmodel * dinner / 8) / 256, 256, 0, stream>>>(
            ow_l, wb_ow, dmodel * dinner / 8);

        // 1) xz = cur @ in_w^T   (2048 x 4096, K=1024) -> f32
        gemm_bf16<0><<<dim3(2 * dinner / 128, BL / 128), 256, 0, stream>>>(
            curb, wb_in, xzb, nullptr, BL, 2 * dinner, dmodel, dmodel, dmodel, 2 * dinner);

        // 2) xc = silu(conv(xr) + cb) -> bf16
        conv_silu<<<(BL * dinner / 4) / 256, 256, 0, stream>>>(
            xzb, cw_l, cb_l, xcb16, Bsz, L, dinner);

        // 3) dbl = xc @ xw^T     (2048 x 96, K=2048) -> f32 + bf16
        gemm_bf16<2><<<dim3(1, BL / 128), 256, 0, stream>>>(
            xcb16, wb_x, dblb, dblb16, BL, 96, dinner, dinner, dinner, 96);

        // 4) dt_raw = dbl[:, :64] @ dtw^T  (2048 x 2048, K=64) -> bf16
        gemm_bf16<1><<<dim3(dinner / 128, BL / 128), 256, 0, stream>>>(
            dblb16, wb_dt, nullptr, dtrb16, BL, dinner, 64, 96, 64, dinner);

        // 5) chunked scan
        scan_part1<<<scan_blocks, 256, 0, stream>>>(
            dtrb16, xcb16, dblb, dtb_l, alog_l, hendb, ssumb, Bsz, L, dinner, NC, CL);
        scan_part2<<<scan_blocks, 256, 0, stream>>>(
            dtrb16, xcb16, dblb, xzb, dtb_l, alog_l, Dp_l, hendb, ssumb,
            Bsz, L, dinner, NC, CL);

        // 6) out = y @ ow^T      (2048 x 1024, K=2048)
        if (l == 0)
            gemm_bf16<1><<<dim3(dmodel / 128, BL / 128), 256, 0, stream>>>(
                dtrb16, wb_ow, nullptr, curb, BL, dmodel, dinner, dinner, dinner, dmodel);
        else
            gemm_bf16<0><<<dim3(dmodel / 128, BL / 128), 256, 0, stream>>>(
                dtrb16, wb_ow, out, nullptr, BL, dmodel, dinner, dinner, dinner, dmodel);
    }
}

// Round 5
// 407.550 us; speedup vs baseline: 7.8460x; 1.6011x over previous
//
#include <hip/hip_runtime.h>
#include <hip/hip_bf16.h>
#include <cmath>

typedef __bf16 bf16x8_t __attribute__((ext_vector_type(8)));
typedef float  f32x4_t  __attribute__((ext_vector_type(4)));
using bf16 = __hip_bfloat16;

#define LOG2E 1.44269504088896340736f
#define LN2   0.69314718055994530942f

__device__ __forceinline__ float fexp2(float x) { return __builtin_amdgcn_exp2f(x); }
__device__ __forceinline__ float flog2(float x) { return __builtin_amdgcn_logf(x); }
__device__ __forceinline__ float frcp (float x) { return __builtin_amdgcn_rcpf(x); }

// ---------------------------------------------------------------------------
// f32 -> bf16 cast, 8 elems/thread
// ---------------------------------------------------------------------------
__global__ __launch_bounds__(256)
void cast_f32_bf16(const float* __restrict__ src, bf16* __restrict__ dst, int n8)
{
    const int i = blockIdx.x * blockDim.x + threadIdx.x;
    if (i >= n8) return;
    const float4* s = (const float4*)(src + (size_t)i * 8);
    float4 a = s[0], b = s[1];
    bf16 o[8];
    o[0] = __float2bfloat16(a.x); o[1] = __float2bfloat16(a.y);
    o[2] = __float2bfloat16(a.z); o[3] = __float2bfloat16(a.w);
    o[4] = __float2bfloat16(b.x); o[5] = __float2bfloat16(b.y);
    o[6] = __float2bfloat16(b.z); o[7] = __float2bfloat16(b.w);
    *(int4*)(dst + (size_t)i * 8) = *(int4*)o;
}

// ---------------------------------------------------------------------------
// bf16 MFMA NT GEMM: C[M,N] = A[M,K] * B[N,K]^T, fp32 accumulate.
// BM=BN=128, BK=32, 4 waves x (64x64), 4x4 frags of 16x16x32.
// ---------------------------------------------------------------------------
template<int MODE>
__global__ __launch_bounds__(256)
void gemm_bf16(const bf16* __restrict__ A, const bf16* __restrict__ B,
               float* __restrict__ Cf, bf16* __restrict__ Cb,
               int M, int N, int K, int lda, int ldb, int ldc)
{
    __shared__ __align__(16) bf16 At[128][40];
    __shared__ __align__(16) bf16 Bt[128][40];

    const int tid  = threadIdx.x;
    const int lane = tid & 63;
    const int wid  = tid >> 6;
    const int wr   = wid >> 1;
    const int wc   = wid & 1;
    const int fr   = lane & 15;
    const int fq   = lane >> 4;

    const int row0 = blockIdx.y * 128;
    const int col0 = blockIdx.x * 128;

    const int srow  = tid >> 1;
    const int shalf = tid & 1;

    const bf16* aptr = A + (size_t)(row0 + srow) * lda + shalf * 16;
    int bRow = col0 + srow; if (bRow >= N) bRow = N - 1;
    const bf16* bptr = B + (size_t)bRow * ldb + shalf * 16;

    f32x4_t acc[4][4];
    #pragma unroll
    for (int m = 0; m < 4; ++m)
        #pragma unroll
        for (int n = 0; n < 4; ++n)
            acc[m][n] = f32x4_t{0.f, 0.f, 0.f, 0.f};

    int4 ra0 = *(const int4*)(aptr);
    int4 ra1 = *(const int4*)(aptr + 8);
    int4 rb0 = *(const int4*)(bptr);
    int4 rb1 = *(const int4*)(bptr + 8);

    for (int k0 = 0; k0 < K; k0 += 32) {
        __syncthreads();
        *(int4*)&At[srow][shalf * 16 + 0] = ra0;
        *(int4*)&At[srow][shalf * 16 + 8] = ra1;
        *(int4*)&Bt[srow][shalf * 16 + 0] = rb0;
        *(int4*)&Bt[srow][shalf * 16 + 8] = rb1;
        __syncthreads();
        if (k0 + 32 < K) {
            ra0 = *(const int4*)(aptr + k0 + 32);
            ra1 = *(const int4*)(aptr + k0 + 40);
            rb0 = *(const int4*)(bptr + k0 + 32);
            rb1 = *(const int4*)(bptr + k0 + 40);
        }
        bf16x8_t af[4], bg[4];
        #pragma unroll
        for (int m = 0; m < 4; ++m)
            af[m] = *(const bf16x8_t*)&At[wr * 64 + m * 16 + fr][fq * 8];
        #pragma unroll
        for (int n = 0; n < 4; ++n)
            bg[n] = *(const bf16x8_t*)&Bt[wc * 64 + n * 16 + fr][fq * 8];
        #pragma unroll
        for (int m = 0; m < 4; ++m)
            #pragma unroll
            for (int n = 0; n < 4; ++n)
                acc[m][n] = __builtin_amdgcn_mfma_f32_16x16x32_bf16(
                    af[m], bg[n], acc[m][n], 0, 0, 0);
    }

    #pragma unroll
    for (int m = 0; m < 4; ++m) {
        #pragma unroll
        for (int n = 0; n < 4; ++n) {
            const int c = col0 + wc * 64 + n * 16 + fr;
            if (c < N) {
                #pragma unroll
                for (int r = 0; r < 4; ++r) {
                    const int rr = row0 + wr * 64 + m * 16 + fq * 4 + r;
                    if (MODE != 1) Cf[(size_t)rr * ldc + c] = acc[m][n][r];
                    if (MODE != 0) Cb[(size_t)rr * ldc + c] = __float2bfloat16(acc[m][n][r]);
                }
            }
        }
    }
}

// ---------------------------------------------------------------------------
// Causal depthwise conv1d (width 4) + bias + SiLU; f32 in, bf16 out.
// ---------------------------------------------------------------------------
__global__ __launch_bounds__(256)
void conv_silu(const float* __restrict__ xz, const float* __restrict__ cw,
               const float* __restrict__ cb, bf16* __restrict__ xc,
               int Bsz, int L, int dinner)
{
    const int nv = dinner / 4;
    const int g  = blockIdx.x * blockDim.x + threadIdx.x;
    const int d4 = (g % nv) * 4;
    const int t  = (g / nv) % L;
    const int b  = g / (nv * L);
    if (b >= Bsz) return;

    const int ldxz = 2 * dinner;
    float4 w0 = *(const float4*)(cw + (size_t)(d4 + 0) * 4);
    float4 w1 = *(const float4*)(cw + (size_t)(d4 + 1) * 4);
    float4 w2 = *(const float4*)(cw + (size_t)(d4 + 2) * 4);
    float4 w3 = *(const float4*)(cw + (size_t)(d4 + 3) * 4);
    float4 acc = *(const float4*)(cb + d4);

    const float* base = xz + (size_t)b * L * ldxz + d4;
    #pragma unroll
    for (int k = 0; k < 4; ++k) {
        const int ts = t - 3 + k;
        if (ts >= 0) {
            float4 v = *(const float4*)(base + (size_t)ts * ldxz);
            acc.x = fmaf(v.x, (&w0.x)[k], acc.x);
            acc.y = fmaf(v.y, (&w1.x)[k], acc.y);
            acc.z = fmaf(v.z, (&w2.x)[k], acc.z);
            acc.w = fmaf(v.w, (&w3.x)[k], acc.w);
        }
    }
    acc.x = acc.x * frcp(1.f + fexp2(-acc.x * LOG2E));
    acc.y = acc.y * frcp(1.f + fexp2(-acc.y * LOG2E));
    acc.z = acc.z * frcp(1.f + fexp2(-acc.z * LOG2E));
    acc.w = acc.w * frcp(1.f + fexp2(-acc.w * LOG2E));

    bf16 o[4];
    o[0] = __float2bfloat16(acc.x); o[1] = __float2bfloat16(acc.y);
    o[2] = __float2bfloat16(acc.z); o[3] = __float2bfloat16(acc.w);
    *(int2*)(xc + ((size_t)b * L + t) * dinner + d4) = *(int2*)o;
}

// ---------------------------------------------------------------------------
// Chunked scan pass 1. Lane = (d_sub*4 + s_quad): each lane owns 4 states of
// one d. Per (b,chunk,d): local scan from h=0; emits chunk-final state hend
// (float4) and (s_quad==0) the softplus-sum S (chunk transition = exp(A*S)).
// ---------------------------------------------------------------------------
__global__ __launch_bounds__(256)
void scan_part1(const bf16* __restrict__ dtraw,   // (B,L,dinner) bf16
                const bf16* __restrict__ xc,      // (B,L,dinner) bf16
                const float* __restrict__ dbl,    // (B,L,96)
                const float* __restrict__ dtb,
                const float* __restrict__ alog,   // (dinner,16)
                float* __restrict__ hend,         // (B,NC,dinner,16)
                float* __restrict__ Ssum,         // (B,NC,dinner)
                int Bsz, int L, int dinner, int NC, int CL)
{
    const int g  = blockIdx.x * blockDim.x + threadIdx.x;
    const int sq = g & 3;
    const int d  = (g >> 2) % dinner;
    const int c  = ((g >> 2) / dinner) % NC;
    const int b  = g / (4 * dinner * NC);
    if (b >= Bsz) return;

    float4 av = *(const float4*)(alog + (size_t)d * 16 + sq * 4);
    // A_s * log2e, pre-negated: dA = exp2(sp * As2)
    const float As0 = -fexp2(av.x * LOG2E) * LOG2E;
    const float As1 = -fexp2(av.y * LOG2E) * LOG2E;
    const float As2 = -fexp2(av.z * LOG2E) * LOG2E;
    const float As3 = -fexp2(av.w * LOG2E) * LOG2E;
    const float bias = dtb[d];

    const int t0 = c * CL;
    const bf16*  dt_p = dtraw + ((size_t)b * L + t0) * dinner + d;
    const bf16*  xc_p = xc    + ((size_t)b * L + t0) * dinner + d;
    const float* bl_p = dbl   + ((size_t)b * L + t0) * 96 + 64 + sq * 4;

    float h0 = 0.f, h1 = 0.f, h2 = 0.f, h3 = 0.f, S = 0.f;
    for (int t = 0; t < CL; ++t) {
        const float dtv = __bfloat162float(*dt_p);
        const float xcv = __bfloat162float(*xc_p);
        const float4 Bv = *(const float4*)bl_p;

        const float xv = dtv + bias;
        const float e  = fexp2(xv * LOG2E);
        const float sp = (xv > 15.f) ? xv : LN2 * flog2(1.f + e);
        S += sp;
        const float u = sp * xcv;
        h0 = fmaf(fexp2(sp * As0), h0, u * Bv.x);
        h1 = fmaf(fexp2(sp * As1), h1, u * Bv.y);
        h2 = fmaf(fexp2(sp * As2), h2, u * Bv.z);
        h3 = fmaf(fexp2(sp * As3), h3, u * Bv.w);

        dt_p += dinner; xc_p += dinner; bl_p += 96;
    }

    const size_t idx = ((size_t)b * NC + c) * dinner + d;
    *(float4*)(hend + idx * 16 + sq * 4) = make_float4(h0, h1, h2, h3);
    if (sq == 0) Ssum[idx] = S;
}

// ---------------------------------------------------------------------------
// Chunk prefix: sequential over NC chunks per (b,d,s). Replaces hend IN PLACE
// with the EXCLUSIVE prefix state (the scan state entering each chunk).
// ---------------------------------------------------------------------------
__global__ __launch_bounds__(256)
void chunk_prefix(float* __restrict__ hend,       // in: chunk-final; out: entry
                  const float* __restrict__ Ssum,
                  const float* __restrict__ alog,
                  int Bsz, int dinner, int NC)
{
    const int g = blockIdx.x * blockDim.x + threadIdx.x;
    const int s = g & 15;
    const int d = (g >> 4) % dinner;
    const int b = g / (16 * dinner);
    if (b >= Bsz) return;

    const float As2 = -fexp2(alog[(size_t)d * 16 + s] * LOG2E) * LOG2E;

    float h = 0.f;
    for (int c = 0; c < NC; ++c) {
        const size_t idx = ((size_t)b * NC + c) * dinner + d;
        const float he = hend[idx * 16 + s];
        const float Sv = Ssum[idx];
        hend[idx * 16 + s] = h;                      // exclusive prefix
        h = fmaf(fexp2(As2 * Sv), h, he);
    }
}

// ---------------------------------------------------------------------------
// Chunked scan pass 2: start from hinit (= prefixed hend), re-scan the chunk,
// reduce over 16 states (4 in-lane + 2 shfl), D-skip, SiLU(z) gate. Writes
// bf16 y IN PLACE over dt_raw (all 4 lockstep lanes load before sq==0 stores).
// ---------------------------------------------------------------------------
__global__ __launch_bounds__(256)
void scan_part2(bf16* dty,                        // (B,L,dinner): dt_raw in, y out
                const bf16* __restrict__ xc,
                const float* __restrict__ dbl,
                const float* __restrict__ xz,     // z = cols dinner.. (f32)
                const float* __restrict__ dtb,
                const float* __restrict__ alog,
                const float* __restrict__ Dp,
                const float* __restrict__ hinit,  // (B,NC,dinner,16) entry states
                int Bsz, int L, int dinner, int NC, int CL)
{
    const int g  = blockIdx.x * blockDim.x + threadIdx.x;
    const int sq = g & 3;
    const int d  = (g >> 2) % dinner;
    const int c  = ((g >> 2) / dinner) % NC;
    const int b  = g / (4 * dinner * NC);
    if (b >= Bsz) return;

    float4 av = *(const float4*)(alog + (size_t)d * 16 + sq * 4);
    const float As0 = -fexp2(av.x * LOG2E) * LOG2E;
    const float As1 = -fexp2(av.y * LOG2E) * LOG2E;
    const float As2 = -fexp2(av.z * LOG2E) * LOG2E;
    const float As3 = -fexp2(av.w * LOG2E) * LOG2E;
    const float bias = dtb[d];
    const float Dval = Dp[d];

    const size_t cidx = ((size_t)b * NC + c) * dinner + d;
    float4 hv = *(const float4*)(hinit + cidx * 16 + sq * 4);
    float h0 = hv.x, h1 = hv.y, h2 = hv.z, h3 = hv.w;

    const int t0 = c * CL;
    bf16*        dt_p = dty + ((size_t)b * L + t0) * dinner + d;
    const bf16*  xc_p = xc  + ((size_t)b * L + t0) * dinner + d;
    const float* bl_p = dbl + ((size_t)b * L + t0) * 96 + 64 + sq * 4;
    const float* z_p  = xz  + ((size_t)b * L + t0) * (2 * dinner) + dinner + d;

    for (int t = 0; t < CL; ++t) {
        const float dtv = __bfloat162float(*dt_p);
        const float xcv = __bfloat162float(*xc_p);
        const float4 Bv = *(const float4*)bl_p;
        const float4 Cv = *(const float4*)(bl_p + 16);
        const float zv  = *z_p;

        const float xv = dtv + bias;
        const float e  = fexp2(xv * LOG2E);
        const float sp = (xv > 15.f) ? xv : LN2 * flog2(1.f + e);
        const float u = sp * xcv;
        h0 = fmaf(fexp2(sp * As0), h0, u * Bv.x);
        h1 = fmaf(fexp2(sp * As1), h1, u * Bv.y);
        h2 = fmaf(fexp2(sp * As2), h2, u * Bv.z);
        h3 = fmaf(fexp2(sp * As3), h3, u * Bv.w);

        float y = h0 * Cv.x + h1 * Cv.y + h2 * Cv.z + h3 * Cv.w;
        y += __shfl_xor(y, 1, 4);
        y += __shfl_xor(y, 2, 4);

        if (sq == 0) {
            y = fmaf(xcv, Dval, y);
            const float sig = frcp(1.f + fexp2(-zv * LOG2E));
            *dt_p = __float2bfloat16(y * (zv * sig));
        }

        dt_p += dinner; xc_p += dinner; bl_p += 96; z_p += 2 * dinner;
    }
}

// ---------------------------------------------------------------------------
extern "C" void kernel_launch(void* const* d_in, const int* in_sizes, int n_in,
                              void* d_out, int out_size, void* d_ws, size_t ws_size,
                              hipStream_t stream)
{
    const float* x    = (const float*)d_in[0];
    const float* inw  = (const float*)d_in[1];
    const float* cw   = (const float*)d_in[2];
    const float* cb   = (const float*)d_in[3];
    const float* xw   = (const float*)d_in[4];
    const float* dtw  = (const float*)d_in[5];
    const float* dtb  = (const float*)d_in[6];
    const float* alog = (const float*)d_in[7];
    const float* Dp   = (const float*)d_in[8];
    const float* ow   = (const float*)d_in[9];
    float* out = (float*)d_out;

    const int Bsz = 2, L = 1024, dmodel = 1024, dinner = 2048;
    const int BL = Bsz * L;            // 2048
    const int NC = 32, CL = L / NC;    // 32 chunks of 32

    // --- workspace layout ---------------------------------------------------
    char* p = (char*)d_ws;
    auto alloc = [&](size_t bytes) { char* r = p; p += (bytes + 63) & ~size_t(63); return r; };
    bf16*  wb_in  = (bf16*) alloc((size_t)2 * dinner * dmodel * 2);
    bf16*  wb_x   = (bf16*) alloc((size_t)96 * dinner * 2);
    bf16*  wb_dt  = (bf16*) alloc((size_t)dinner * 64 * 2);
    bf16*  wb_ow  = (bf16*) alloc((size_t)dmodel * dinner * 2);
    bf16*  curb   = (bf16*) alloc((size_t)BL * dmodel * 2);
    float* xzb    = (float*)alloc((size_t)BL * 2 * dinner * 4);
    bf16*  xcb16  = (bf16*) alloc((size_t)BL * dinner * 2);
    float* dblb   = (float*)alloc((size_t)BL * 96 * 4);
    bf16*  dblb16 = (bf16*) alloc((size_t)BL * 96 * 2);
    bf16*  dtrb16 = (bf16*) alloc((size_t)BL * dinner * 2);
    float* hendb  = (float*)alloc((size_t)Bsz * NC * dinner * 16 * 4);
    float* ssumb  = (float*)alloc((size_t)Bsz * NC * dinner * 4);

    const int scan_blocks = (Bsz * NC * dinner * 4) / 256;    // 2048
    const int pfx_blocks  = (Bsz * dinner * 16) / 256;        // 256

    cast_f32_bf16<<<(BL * dmodel / 8) / 256, 256, 0, stream>>>(x, curb, BL * dmodel / 8);

    for (int l = 0; l < 2; ++l) {
        const float* inw_l  = inw  + (size_t)l * 2 * dinner * dmodel;
        const float* cw_l   = cw   + (size_t)l * dinner * 4;
        const float* cb_l   = cb   + (size_t)l * dinner;
        const float* xw_l   = xw   + (size_t)l * 96 * dinner;
        const float* dtw_l  = dtw  + (size_t)l * dinner * 64;
        const float* dtb_l  = dtb  + (size_t)l * dinner;
        const float* alog_l = alog + (size_t)l * dinner * 16;
        const float* Dp_l   = Dp   + (size_t)l * dinner;
        const float* ow_l   = ow   + (size_t)l * dmodel * dinner;

        cast_f32_bf16<<<(2 * dinner * dmodel / 8) / 256, 256, 0, stream>>>(
            inw_l, wb_in, 2 * dinner * dmodel / 8);
        cast_f32_bf16<<<(96 * dinner / 8) / 256, 256, 0, stream>>>(
            xw_l, wb_x, 96 * dinner / 8);
        cast_f32_bf16<<<(dinner * 64 / 8) / 256, 256, 0, stream>>>(
            dtw_l, wb_dt, dinner * 64 / 8);
        cast_f32_bf16<<<(dmodel * dinner / 8) / 256, 256, 0, stream>>>(
            ow_l, wb_ow, dmodel * dinner / 8);

        // 1) xz = cur @ in_w^T   (2048 x 4096, K=1024) -> f32
        gemm_bf16<0><<<dim3(2 * dinner / 128, BL / 128), 256, 0, stream>>>(
            curb, wb_in, xzb, nullptr, BL, 2 * dinner, dmodel, dmodel, dmodel, 2 * dinner);

        // 2) xc = silu(conv(xr) + cb) -> bf16
        conv_silu<<<(BL * dinner / 4) / 256, 256, 0, stream>>>(
            xzb, cw_l, cb_l, xcb16, Bsz, L, dinner);

        // 3) dbl = xc @ xw^T     (2048 x 96, K=2048) -> f32 + bf16
        gemm_bf16<2><<<dim3(1, BL / 128), 256, 0, stream>>>(
            xcb16, wb_x, dblb, dblb16, BL, 96, dinner, dinner, dinner, 96);

        // 4) dt_raw = dbl[:, :64] @ dtw^T  (2048 x 2048, K=64) -> bf16
        gemm_bf16<1><<<dim3(dinner / 128, BL / 128), 256, 0, stream>>>(
            dblb16, wb_dt, nullptr, dtrb16, BL, dinner, 64, 96, 64, dinner);

        // 5) chunked scan: local scans -> chunk prefix -> final pass
        scan_part1<<<scan_blocks, 256, 0, stream>>>(
            dtrb16, xcb16, dblb, dtb_l, alog_l, hendb, ssumb, Bsz, L, dinner, NC, CL);
        chunk_prefix<<<pfx_blocks, 256, 0, stream>>>(
            hendb, ssumb, alog_l, Bsz, dinner, NC);
        scan_part2<<<scan_blocks, 256, 0, stream>>>(
            dtrb16, xcb16, dblb, xzb, dtb_l, alog_l, Dp_l, hendb,
            Bsz, L, dinner, NC, CL);

        // 6) out = y @ ow^T      (2048 x 1024, K=2048)
        if (l == 0)
            gemm_bf16<1><<<dim3(dmodel / 128, BL / 128), 256, 0, stream>>>(
                dtrb16, wb_ow, nullptr, curb, BL, dmodel, dinner, dinner, dinner, dmodel);
        else
            gemm_bf16<0><<<dim3(dmodel / 128, BL / 128), 256, 0, stream>>>(
                dtrb16, wb_ow, out, nullptr, BL, dmodel, dinner, dinner, dinner, dmodel);
    }
}

// Round 6
// 383.026 us; speedup vs baseline: 8.3484x; 1.0640x over previous
//
#include <hip/hip_runtime.h>
#include <hip/hip_bf16.h>
#include <cmath>

typedef __bf16 bf16x8_t __attribute__((ext_vector_type(8)));
typedef float  f32x4_t  __attribute__((ext_vector_type(4)));
using bf16 = __hip_bfloat16;

#define LOG2E 1.44269504088896340736f
#define LN2   0.69314718055994530942f

#define AS1C(p) ((const __attribute__((address_space(1))) void*)(p))
#define AS3C(p) ((__attribute__((address_space(3))) void*)(p))

__device__ __forceinline__ float fexp2(float x) { return __builtin_amdgcn_exp2f(x); }
__device__ __forceinline__ float flog2(float x) { return __builtin_amdgcn_logf(x); }
__device__ __forceinline__ float frcp (float x) { return __builtin_amdgcn_rcpf(x); }

// ---------------------------------------------------------------------------
// f32 -> bf16 cast, 8 elems/thread
// ---------------------------------------------------------------------------
__global__ __launch_bounds__(256)
void cast_f32_bf16(const float* __restrict__ src, bf16* __restrict__ dst, int n8)
{
    const int i = blockIdx.x * blockDim.x + threadIdx.x;
    if (i >= n8) return;
    const float4* s = (const float4*)(src + (size_t)i * 8);
    float4 a = s[0], b = s[1];
    bf16 o[8];
    o[0] = __float2bfloat16(a.x); o[1] = __float2bfloat16(a.y);
    o[2] = __float2bfloat16(a.z); o[3] = __float2bfloat16(a.w);
    o[4] = __float2bfloat16(b.x); o[5] = __float2bfloat16(b.y);
    o[6] = __float2bfloat16(b.z); o[7] = __float2bfloat16(b.w);
    *(int4*)(dst + (size_t)i * 8) = *(int4*)o;
}

// ---------------------------------------------------------------------------
// bf16 MFMA NT GEMM with async global->LDS staging (m97 structure).
// C[M,N] = A[M,K] * B[N,K]^T. BM=BN=128, BK=32, 4 waves x (64x64).
// LDS tiles are LINEAR [128][32] (global_load_lds writes base + lane*16B).
// Per K-step, wave w stages rows [w*32, w*32+32) of A and B:
//   lane l -> row w*32 + issue*16 + (l>>2), k-part (l&3)*8 elems (16B).
// MODE: 0 = f32 store, 1 = bf16 store. N bounds-checked.
// ---------------------------------------------------------------------------
template<int MODE>
__global__ __launch_bounds__(256)
void gemm_bf16(const bf16* __restrict__ A, const bf16* __restrict__ B,
               float* __restrict__ Cf, bf16* __restrict__ Cb,
               int M, int N, int K, int lda, int ldb, int ldc)
{
    __shared__ __align__(16) bf16 At[128][32];
    __shared__ __align__(16) bf16 Bt[128][32];

    const int tid  = threadIdx.x;
    const int lane = tid & 63;
    const int wid  = tid >> 6;
    const int wr   = wid >> 1;
    const int wc   = wid & 1;
    const int fr   = lane & 15;
    const int fq   = lane >> 4;

    const int row0 = blockIdx.y * 128;
    const int col0 = blockIdx.x * 128;

    // async-staging addressing
    const int g_row = wid * 32 + (lane >> 2);      // first 16-row issue
    const int g_kp  = (lane & 3) * 8;              // 8 bf16 = 16B
    const bf16* aP0 = A + (size_t)(row0 + g_row) * lda + g_kp;
    const bf16* aP1 = A + (size_t)(row0 + g_row + 16) * lda + g_kp;
    int bR0 = col0 + g_row;      if (bR0 >= N) bR0 = N - 1;
    int bR1 = col0 + g_row + 16; if (bR1 >= N) bR1 = N - 1;
    const bf16* bP0 = B + (size_t)bR0 * ldb + g_kp;
    const bf16* bP1 = B + (size_t)bR1 * ldb + g_kp;

    bf16* aL0 = &At[wid * 32][0];        // wave-uniform LDS bases
    bf16* aL1 = &At[wid * 32 + 16][0];
    bf16* bL0 = &Bt[wid * 32][0];
    bf16* bL1 = &Bt[wid * 32 + 16][0];

    f32x4_t acc[4][4];
    #pragma unroll
    for (int m = 0; m < 4; ++m)
        #pragma unroll
        for (int n = 0; n < 4; ++n)
            acc[m][n] = f32x4_t{0.f, 0.f, 0.f, 0.f};

    for (int k0 = 0; k0 < K; k0 += 32) {
        __syncthreads();    // previous iteration's frag reads complete
        __builtin_amdgcn_global_load_lds(AS1C(aP0 + k0), AS3C(aL0), 16, 0, 0);
        __builtin_amdgcn_global_load_lds(AS1C(aP1 + k0), AS3C(aL1), 16, 0, 0);
        __builtin_amdgcn_global_load_lds(AS1C(bP0 + k0), AS3C(bL0), 16, 0, 0);
        __builtin_amdgcn_global_load_lds(AS1C(bP1 + k0), AS3C(bL1), 16, 0, 0);
        __syncthreads();    // compiler drains vmcnt before barrier -> LDS ready

        bf16x8_t af[4], bg[4];
        #pragma unroll
        for (int m = 0; m < 4; ++m)
            af[m] = *(const bf16x8_t*)&At[wr * 64 + m * 16 + fr][fq * 8];
        #pragma unroll
        for (int n = 0; n < 4; ++n)
            bg[n] = *(const bf16x8_t*)&Bt[wc * 64 + n * 16 + fr][fq * 8];
        #pragma unroll
        for (int m = 0; m < 4; ++m)
            #pragma unroll
            for (int n = 0; n < 4; ++n)
                acc[m][n] = __builtin_amdgcn_mfma_f32_16x16x32_bf16(
                    af[m], bg[n], acc[m][n], 0, 0, 0);
    }

    // C/D layout: col = lane&15, row = (lane>>4)*4 + reg
    #pragma unroll
    for (int m = 0; m < 4; ++m) {
        #pragma unroll
        for (int n = 0; n < 4; ++n) {
            const int c = col0 + wc * 64 + n * 16 + fr;
            if (c < N) {
                #pragma unroll
                for (int r = 0; r < 4; ++r) {
                    const int rr = row0 + wr * 64 + m * 16 + fq * 4 + r;
                    if (MODE != 1) Cf[(size_t)rr * ldc + c] = acc[m][n][r];
                    if (MODE != 0) Cb[(size_t)rr * ldc + c] = __float2bfloat16(acc[m][n][r]);
                }
            }
        }
    }
}

// ---------------------------------------------------------------------------
// Split-K variant for the skinny x_proj GEMM (N=96): blockIdx.z = K-segment,
// partial f32 results to Cp[z][M][ldc]. Same staging structure.
// ---------------------------------------------------------------------------
__global__ __launch_bounds__(256)
void gemm_bf16_pk(const bf16* __restrict__ A, const bf16* __restrict__ B,
                  float* __restrict__ Cp, int M, int N, int Kseg,
                  int lda, int ldb, int ldc)
{
    __shared__ __align__(16) bf16 At[128][32];
    __shared__ __align__(16) bf16 Bt[128][32];

    const int tid  = threadIdx.x;
    const int lane = tid & 63;
    const int wid  = tid >> 6;
    const int wr   = wid >> 1;
    const int wc   = wid & 1;
    const int fr   = lane & 15;
    const int fq   = lane >> 4;

    const int row0 = blockIdx.y * 128;
    const int col0 = blockIdx.x * 128;
    const int kb   = blockIdx.z * Kseg;

    const int g_row = wid * 32 + (lane >> 2);
    const int g_kp  = (lane & 3) * 8;
    const bf16* aP0 = A + (size_t)(row0 + g_row) * lda + g_kp + kb;
    const bf16* aP1 = A + (size_t)(row0 + g_row + 16) * lda + g_kp + kb;
    int bR0 = col0 + g_row;      if (bR0 >= N) bR0 = N - 1;
    int bR1 = col0 + g_row + 16; if (bR1 >= N) bR1 = N - 1;
    const bf16* bP0 = B + (size_t)bR0 * ldb + g_kp + kb;
    const bf16* bP1 = B + (size_t)bR1 * ldb + g_kp + kb;

    bf16* aL0 = &At[wid * 32][0];
    bf16* aL1 = &At[wid * 32 + 16][0];
    bf16* bL0 = &Bt[wid * 32][0];
    bf16* bL1 = &Bt[wid * 32 + 16][0];

    f32x4_t acc[4][4];
    #pragma unroll
    for (int m = 0; m < 4; ++m)
        #pragma unroll
        for (int n = 0; n < 4; ++n)
            acc[m][n] = f32x4_t{0.f, 0.f, 0.f, 0.f};

    for (int k0 = 0; k0 < Kseg; k0 += 32) {
        __syncthreads();
        __builtin_amdgcn_global_load_lds(AS1C(aP0 + k0), AS3C(aL0), 16, 0, 0);
        __builtin_amdgcn_global_load_lds(AS1C(aP1 + k0), AS3C(aL1), 16, 0, 0);
        __builtin_amdgcn_global_load_lds(AS1C(bP0 + k0), AS3C(bL0), 16, 0, 0);
        __builtin_amdgcn_global_load_lds(AS1C(bP1 + k0), AS3C(bL1), 16, 0, 0);
        __syncthreads();

        bf16x8_t af[4], bg[4];
        #pragma unroll
        for (int m = 0; m < 4; ++m)
            af[m] = *(const bf16x8_t*)&At[wr * 64 + m * 16 + fr][fq * 8];
        #pragma unroll
        for (int n = 0; n < 4; ++n)
            bg[n] = *(const bf16x8_t*)&Bt[wc * 64 + n * 16 + fr][fq * 8];
        #pragma unroll
        for (int m = 0; m < 4; ++m)
            #pragma unroll
            for (int n = 0; n < 4; ++n)
                acc[m][n] = __builtin_amdgcn_mfma_f32_16x16x32_bf16(
                    af[m], bg[n], acc[m][n], 0, 0, 0);
    }

    float* Cz = Cp + (size_t)blockIdx.z * M * ldc;
    #pragma unroll
    for (int m = 0; m < 4; ++m) {
        #pragma unroll
        for (int n = 0; n < 4; ++n) {
            const int c = col0 + wc * 64 + n * 16 + fr;
            if (c < N) {
                #pragma unroll
                for (int r = 0; r < 4; ++r) {
                    const int rr = row0 + wr * 64 + m * 16 + fq * 4 + r;
                    Cz[(size_t)rr * ldc + c] = acc[m][n][r];
                }
            }
        }
    }
}

// ---------------------------------------------------------------------------
// Reduce split-K partials -> f32 + bf16 outputs.
// ---------------------------------------------------------------------------
__global__ __launch_bounds__(256)
void reduce_xproj(const float* __restrict__ part, float* __restrict__ of,
                  bf16* __restrict__ oh, int n, int stride, int S)
{
    const int i = blockIdx.x * blockDim.x + threadIdx.x;
    if (i >= n) return;
    float s = 0.f;
    for (int k = 0; k < S; ++k) s += part[(size_t)k * stride + i];
    of[i] = s;
    oh[i] = __float2bfloat16(s);
}

// ---------------------------------------------------------------------------
// Causal depthwise conv1d (width 4) + bias + SiLU; f32 in, bf16 out.
// ---------------------------------------------------------------------------
__global__ __launch_bounds__(256)
void conv_silu(const float* __restrict__ xz, const float* __restrict__ cw,
               const float* __restrict__ cb, bf16* __restrict__ xc,
               int Bsz, int L, int dinner)
{
    const int nv = dinner / 4;
    const int g  = blockIdx.x * blockDim.x + threadIdx.x;
    const int d4 = (g % nv) * 4;
    const int t  = (g / nv) % L;
    const int b  = g / (nv * L);
    if (b >= Bsz) return;

    const int ldxz = 2 * dinner;
    float4 w0 = *(const float4*)(cw + (size_t)(d4 + 0) * 4);
    float4 w1 = *(const float4*)(cw + (size_t)(d4 + 1) * 4);
    float4 w2 = *(const float4*)(cw + (size_t)(d4 + 2) * 4);
    float4 w3 = *(const float4*)(cw + (size_t)(d4 + 3) * 4);
    float4 acc = *(const float4*)(cb + d4);

    const float* base = xz + (size_t)b * L * ldxz + d4;
    #pragma unroll
    for (int k = 0; k < 4; ++k) {
        const int ts = t - 3 + k;
        if (ts >= 0) {
            float4 v = *(const float4*)(base + (size_t)ts * ldxz);
            acc.x = fmaf(v.x, (&w0.x)[k], acc.x);
            acc.y = fmaf(v.y, (&w1.x)[k], acc.y);
            acc.z = fmaf(v.z, (&w2.x)[k], acc.z);
            acc.w = fmaf(v.w, (&w3.x)[k], acc.w);
        }
    }
    acc.x = acc.x * frcp(1.f + fexp2(-acc.x * LOG2E));
    acc.y = acc.y * frcp(1.f + fexp2(-acc.y * LOG2E));
    acc.z = acc.z * frcp(1.f + fexp2(-acc.z * LOG2E));
    acc.w = acc.w * frcp(1.f + fexp2(-acc.w * LOG2E));

    bf16 o[4];
    o[0] = __float2bfloat16(acc.x); o[1] = __float2bfloat16(acc.y);
    o[2] = __float2bfloat16(acc.z); o[3] = __float2bfloat16(acc.w);
    *(int2*)(xc + ((size_t)b * L + t) * dinner + d4) = *(int2*)o;
}

// ---------------------------------------------------------------------------
// Chunked scan pass 1: lane owns 4 states of one d; local scan from h=0;
// emits chunk-final state and (sq==0) the softplus-sum S.
// ---------------------------------------------------------------------------
__global__ __launch_bounds__(256)
void scan_part1(const bf16* __restrict__ dtraw, const bf16* __restrict__ xc,
                const float* __restrict__ dbl, const float* __restrict__ dtb,
                const float* __restrict__ alog, float* __restrict__ hend,
                float* __restrict__ Ssum, int Bsz, int L, int dinner,
                int NC, int CL)
{
    const int g  = blockIdx.x * blockDim.x + threadIdx.x;
    const int sq = g & 3;
    const int d  = (g >> 2) % dinner;
    const int c  = ((g >> 2) / dinner) % NC;
    const int b  = g / (4 * dinner * NC);
    if (b >= Bsz) return;

    float4 av = *(const float4*)(alog + (size_t)d * 16 + sq * 4);
    const float As0 = -fexp2(av.x * LOG2E) * LOG2E;
    const float As1 = -fexp2(av.y * LOG2E) * LOG2E;
    const float As2 = -fexp2(av.z * LOG2E) * LOG2E;
    const float As3 = -fexp2(av.w * LOG2E) * LOG2E;
    const float bias = dtb[d];

    const int t0 = c * CL;
    const bf16*  dt_p = dtraw + ((size_t)b * L + t0) * dinner + d;
    const bf16*  xc_p = xc    + ((size_t)b * L + t0) * dinner + d;
    const float* bl_p = dbl   + ((size_t)b * L + t0) * 96 + 64 + sq * 4;

    float h0 = 0.f, h1 = 0.f, h2 = 0.f, h3 = 0.f, S = 0.f;
    for (int t = 0; t < CL; ++t) {
        const float dtv = __bfloat162float(*dt_p);
        const float xcv = __bfloat162float(*xc_p);
        const float4 Bv = *(const float4*)bl_p;

        const float xv = dtv + bias;
        const float e  = fexp2(xv * LOG2E);
        const float sp = (xv > 15.f) ? xv : LN2 * flog2(1.f + e);
        S += sp;
        const float u = sp * xcv;
        h0 = fmaf(fexp2(sp * As0), h0, u * Bv.x);
        h1 = fmaf(fexp2(sp * As1), h1, u * Bv.y);
        h2 = fmaf(fexp2(sp * As2), h2, u * Bv.z);
        h3 = fmaf(fexp2(sp * As3), h3, u * Bv.w);

        dt_p += dinner; xc_p += dinner; bl_p += 96;
    }

    const size_t idx = ((size_t)b * NC + c) * dinner + d;
    *(float4*)(hend + idx * 16 + sq * 4) = make_float4(h0, h1, h2, h3);
    if (sq == 0) Ssum[idx] = S;
}

// ---------------------------------------------------------------------------
// Chunk prefix: replaces hend IN PLACE with the EXCLUSIVE prefix state.
// ---------------------------------------------------------------------------
__global__ __launch_bounds__(256)
void chunk_prefix(float* __restrict__ hend, const float* __restrict__ Ssum,
                  const float* __restrict__ alog, int Bsz, int dinner, int NC)
{
    const int g = blockIdx.x * blockDim.x + threadIdx.x;
    const int s = g & 15;
    const int d = (g >> 4) % dinner;
    const int b = g / (16 * dinner);
    if (b >= Bsz) return;

    const float As2 = -fexp2(alog[(size_t)d * 16 + s] * LOG2E) * LOG2E;

    float h = 0.f;
    for (int c = 0; c < NC; ++c) {
        const size_t idx = ((size_t)b * NC + c) * dinner + d;
        const float he = hend[idx * 16 + s];
        const float Sv = Ssum[idx];
        hend[idx * 16 + s] = h;
        h = fmaf(fexp2(As2 * Sv), h, he);
    }
}

// ---------------------------------------------------------------------------
// Chunked scan pass 2: start from entry state, re-scan, reduce 16 states
// (4 in-lane + 2 shfl), D-skip, SiLU(z) gate; bf16 y in place over dt_raw.
// ---------------------------------------------------------------------------
__global__ __launch_bounds__(256)
void scan_part2(bf16* dty, const bf16* __restrict__ xc,
                const float* __restrict__ dbl, const float* __restrict__ xz,
                const float* __restrict__ dtb, const float* __restrict__ alog,
                const float* __restrict__ Dp, const float* __restrict__ hinit,
                int Bsz, int L, int dinner, int NC, int CL)
{
    const int g  = blockIdx.x * blockDim.x + threadIdx.x;
    const int sq = g & 3;
    const int d  = (g >> 2) % dinner;
    const int c  = ((g >> 2) / dinner) % NC;
    const int b  = g / (4 * dinner * NC);
    if (b >= Bsz) return;

    float4 av = *(const float4*)(alog + (size_t)d * 16 + sq * 4);
    const float As0 = -fexp2(av.x * LOG2E) * LOG2E;
    const float As1 = -fexp2(av.y * LOG2E) * LOG2E;
    const float As2 = -fexp2(av.z * LOG2E) * LOG2E;
    const float As3 = -fexp2(av.w * LOG2E) * LOG2E;
    const float bias = dtb[d];
    const float Dval = Dp[d];

    const size_t cidx = ((size_t)b * NC + c) * dinner + d;
    float4 hv = *(const float4*)(hinit + cidx * 16 + sq * 4);
    float h0 = hv.x, h1 = hv.y, h2 = hv.z, h3 = hv.w;

    const int t0 = c * CL;
    bf16*        dt_p = dty + ((size_t)b * L + t0) * dinner + d;
    const bf16*  xc_p = xc  + ((size_t)b * L + t0) * dinner + d;
    const float* bl_p = dbl + ((size_t)b * L + t0) * 96 + 64 + sq * 4;
    const float* z_p  = xz  + ((size_t)b * L + t0) * (2 * dinner) + dinner + d;

    for (int t = 0; t < CL; ++t) {
        const float dtv = __bfloat162float(*dt_p);
        const float xcv = __bfloat162float(*xc_p);
        const float4 Bv = *(const float4*)bl_p;
        const float4 Cv = *(const float4*)(bl_p + 16);
        const float zv  = *z_p;

        const float xv = dtv + bias;
        const float e  = fexp2(xv * LOG2E);
        const float sp = (xv > 15.f) ? xv : LN2 * flog2(1.f + e);
        const float u = sp * xcv;
        h0 = fmaf(fexp2(sp * As0), h0, u * Bv.x);
        h1 = fmaf(fexp2(sp * As1), h1, u * Bv.y);
        h2 = fmaf(fexp2(sp * As2), h2, u * Bv.z);
        h3 = fmaf(fexp2(sp * As3), h3, u * Bv.w);

        float y = h0 * Cv.x + h1 * Cv.y + h2 * Cv.z + h3 * Cv.w;
        y += __shfl_xor(y, 1, 4);
        y += __shfl_xor(y, 2, 4);

        if (sq == 0) {
            y = fmaf(xcv, Dval, y);
            const float sig = frcp(1.f + fexp2(-zv * LOG2E));
            *dt_p = __float2bfloat16(y * (zv * sig));
        }

        dt_p += dinner; xc_p += dinner; bl_p += 96; z_p += 2 * dinner;
    }
}

// ---------------------------------------------------------------------------
extern "C" void kernel_launch(void* const* d_in, const int* in_sizes, int n_in,
                              void* d_out, int out_size, void* d_ws, size_t ws_size,
                              hipStream_t stream)
{
    const float* x    = (const float*)d_in[0];
    const float* inw  = (const float*)d_in[1];
    const float* cw   = (const float*)d_in[2];
    const float* cb   = (const float*)d_in[3];
    const float* xw   = (const float*)d_in[4];
    const float* dtw  = (const float*)d_in[5];
    const float* dtb  = (const float*)d_in[6];
    const float* alog = (const float*)d_in[7];
    const float* Dp   = (const float*)d_in[8];
    const float* ow   = (const float*)d_in[9];
    float* out = (float*)d_out;

    const int Bsz = 2, L = 1024, dmodel = 1024, dinner = 2048;
    const int BL = Bsz * L;            // 2048
    const int NC = 32, CL = L / NC;    // 32 chunks of 32
    const int SPLIT = 8, KSEG = dinner / SPLIT;   // x_proj split-K

    // --- workspace layout ---------------------------------------------------
    char* p = (char*)d_ws;
    auto alloc = [&](size_t bytes) { char* r = p; p += (bytes + 63) & ~size_t(63); return r; };
    bf16*  wb_in  = (bf16*) alloc((size_t)2 * 2 * dinner * dmodel * 2);   // both layers
    bf16*  wb_x   = (bf16*) alloc((size_t)2 * 96 * dinner * 2);
    bf16*  wb_dt  = (bf16*) alloc((size_t)2 * dinner * 64 * 2);
    bf16*  wb_ow  = (bf16*) alloc((size_t)2 * dmodel * dinner * 2);
    bf16*  curb   = (bf16*) alloc((size_t)BL * dmodel * 2);
    float* xzb    = (float*)alloc((size_t)BL * 2 * dinner * 4);
    bf16*  xcb16  = (bf16*) alloc((size_t)BL * dinner * 2);
    float* dblb   = (float*)alloc((size_t)BL * 96 * 4);
    bf16*  dblb16 = (bf16*) alloc((size_t)BL * 96 * 2);
    bf16*  dtrb16 = (bf16*) alloc((size_t)BL * dinner * 2);
    float* hendb  = (float*)alloc((size_t)Bsz * NC * dinner * 16 * 4);
    float* ssumb  = (float*)alloc((size_t)Bsz * NC * dinner * 4);
    float* partb  = (float*)alloc((size_t)SPLIT * BL * 96 * 4);

    const int scan_blocks = (Bsz * NC * dinner * 4) / 256;    // 2048
    const int pfx_blocks  = (Bsz * dinner * 16) / 256;        // 256

    // ---- all casts up front (weights are layer-contiguous) ----
    cast_f32_bf16<<<(BL * dmodel / 8) / 256, 256, 0, stream>>>(x, curb, BL * dmodel / 8);
    cast_f32_bf16<<<(2 * 2 * dinner * dmodel / 8) / 256, 256, 0, stream>>>(
        inw, wb_in, 2 * 2 * dinner * dmodel / 8);
    cast_f32_bf16<<<(2 * 96 * dinner / 8) / 256, 256, 0, stream>>>(
        xw, wb_x, 2 * 96 * dinner / 8);
    cast_f32_bf16<<<(2 * dinner * 64 / 8) / 256, 256, 0, stream>>>(
        dtw, wb_dt, 2 * dinner * 64 / 8);
    cast_f32_bf16<<<(2 * dmodel * dinner / 8) / 256, 256, 0, stream>>>(
        ow, wb_ow, 2 * dmodel * dinner / 8);

    for (int l = 0; l < 2; ++l) {
        const bf16*  wb_in_l = wb_in + (size_t)l * 2 * dinner * dmodel;
        const bf16*  wb_x_l  = wb_x  + (size_t)l * 96 * dinner;
        const bf16*  wb_dt_l = wb_dt + (size_t)l * dinner * 64;
        const bf16*  wb_ow_l = wb_ow + (size_t)l * dmodel * dinner;
        const float* cw_l    = cw   + (size_t)l * dinner * 4;
        const float* cb_l    = cb   + (size_t)l * dinner;
        const float* dtb_l   = dtb  + (size_t)l * dinner;
        const float* alog_l  = alog + (size_t)l * dinner * 16;
        const float* Dp_l    = Dp   + (size_t)l * dinner;

        // 1) xz = cur @ in_w^T   (2048 x 4096, K=1024) -> f32
        gemm_bf16<0><<<dim3(2 * dinner / 128, BL / 128), 256, 0, stream>>>(
            curb, wb_in_l, xzb, nullptr, BL, 2 * dinner, dmodel, dmodel, dmodel, 2 * dinner);

        // 2) xc = silu(conv(xr) + cb) -> bf16
        conv_silu<<<(BL * dinner / 4) / 256, 256, 0, stream>>>(
            xzb, cw_l, cb_l, xcb16, Bsz, L, dinner);

        // 3) dbl = xc @ xw^T     (2048 x 96, K=2048), split-K + reduce
        gemm_bf16_pk<<<dim3(1, BL / 128, SPLIT), 256, 0, stream>>>(
            xcb16, wb_x_l, partb, BL, 96, KSEG, dinner, dinner, 96);
        reduce_xproj<<<(BL * 96 + 255) / 256, 256, 0, stream>>>(
            partb, dblb, dblb16, BL * 96, BL * 96, SPLIT);

        // 4) dt_raw = dbl[:, :64] @ dtw^T  (2048 x 2048, K=64) -> bf16
        gemm_bf16<1><<<dim3(dinner / 128, BL / 128), 256, 0, stream>>>(
            dblb16, wb_dt_l, nullptr, dtrb16, BL, dinner, 64, 96, 64, dinner);

        // 5) chunked scan: local scans -> chunk prefix -> final pass
        scan_part1<<<scan_blocks, 256, 0, stream>>>(
            dtrb16, xcb16, dblb, dtb_l, alog_l, hendb, ssumb, Bsz, L, dinner, NC, CL);
        chunk_prefix<<<pfx_blocks, 256, 0, stream>>>(
            hendb, ssumb, alog_l, Bsz, dinner, NC);
        scan_part2<<<scan_blocks, 256, 0, stream>>>(
            dtrb16, xcb16, dblb, xzb, dtb_l, alog_l, Dp_l, hendb,
            Bsz, L, dinner, NC, CL);

        // 6) out = y @ ow^T      (2048 x 1024, K=2048)
        if (l == 0)
            gemm_bf16<1><<<dim3(dmodel / 128, BL / 128), 256, 0, stream>>>(
                dtrb16, wb_ow_l, nullptr, curb, BL, dmodel, dinner, dinner, dinner, dmodel);
        else
            gemm_bf16<0><<<dim3(dmodel / 128, BL / 128), 256, 0, stream>>>(
                dtrb16, wb_ow_l, out, nullptr, BL, dmodel, dinner, dinner, dinner, dmodel);
    }
}

// Round 7
// 342.968 us; speedup vs baseline: 9.3234x; 1.1168x over previous
//
#include <hip/hip_runtime.h>
#include <hip/hip_bf16.h>
#include <cmath>

typedef __bf16 bf16x8_t __attribute__((ext_vector_type(8)));
typedef float  f32x4_t  __attribute__((ext_vector_type(4)));
using bf16 = __hip_bfloat16;

#define LOG2E 1.44269504088896340736f
#define LN2   0.69314718055994530942f

#define AS1C(p) ((const __attribute__((address_space(1))) void*)(p))
#define AS3C(p) ((__attribute__((address_space(3))) void*)(p))

__device__ __forceinline__ float fexp2(float x) { return __builtin_amdgcn_exp2f(x); }
__device__ __forceinline__ float flog2(float x) { return __builtin_amdgcn_logf(x); }
__device__ __forceinline__ float frcp (float x) { return __builtin_amdgcn_rcpf(x); }

// ---------------------------------------------------------------------------
// f32 -> bf16 cast, 8 elems/thread
// ---------------------------------------------------------------------------
__global__ __launch_bounds__(256)
void cast_f32_bf16(const float* __restrict__ src, bf16* __restrict__ dst, int n8)
{
    const int i = blockIdx.x * blockDim.x + threadIdx.x;
    if (i >= n8) return;
    const float4* s = (const float4*)(src + (size_t)i * 8);
    float4 a = s[0], b = s[1];
    bf16 o[8];
    o[0] = __float2bfloat16(a.x); o[1] = __float2bfloat16(a.y);
    o[2] = __float2bfloat16(a.z); o[3] = __float2bfloat16(a.w);
    o[4] = __float2bfloat16(b.x); o[5] = __float2bfloat16(b.y);
    o[6] = __float2bfloat16(b.z); o[7] = __float2bfloat16(b.w);
    *(int4*)(dst + (size_t)i * 8) = *(int4*)o;
}

// ---------------------------------------------------------------------------
// bf16 MFMA NT GEMM, 2-phase double-buffered async staging.
// C[M,N] = A[M,K] * B[N,K]^T. BM=BN=128, BK=32, 4 waves x (64x64).
// LDS [2][128][32] linear; global_load_lds dest = wave-uniform base + lane*16B.
// Loop: STAGE(next) -> ds_read+MFMA(cur) -> __syncthreads (drains vmcnt) -> flip.
// SPLITK: blockIdx.z selects a K-segment; f32 partial to Cf + z*M*ldc.
// MODE: 0 = f32 store, 1 = bf16 store (ignored when SPLITK).
// ---------------------------------------------------------------------------
template<int MODE, bool SPLITK>
__global__ __launch_bounds__(256)
void gemm_bf16(const bf16* __restrict__ A, const bf16* __restrict__ B,
               float* __restrict__ Cf, bf16* __restrict__ Cb,
               int M, int N, int K, int lda, int ldb, int ldc)
{
    __shared__ __align__(16) bf16 At[2][128][32];
    __shared__ __align__(16) bf16 Bt[2][128][32];

    const int tid  = threadIdx.x;
    const int lane = tid & 63;
    const int wid  = tid >> 6;
    const int wr   = wid >> 1;
    const int wc   = wid & 1;
    const int fr   = lane & 15;
    const int fq   = lane >> 4;

    const int row0 = blockIdx.y * 128;
    const int col0 = blockIdx.x * 128;
    const int kb   = SPLITK ? blockIdx.z * K : 0;   // K = segment length when SPLITK

    const int g_row = wid * 32 + (lane >> 2);
    const int g_kp  = (lane & 3) * 8;
    const bf16* aP0 = A + (size_t)(row0 + g_row) * lda + g_kp + kb;
    const bf16* aP1 = A + (size_t)(row0 + g_row + 16) * lda + g_kp + kb;
    int bR0 = col0 + g_row;      if (bR0 >= N) bR0 = N - 1;
    int bR1 = col0 + g_row + 16; if (bR1 >= N) bR1 = N - 1;
    const bf16* bP0 = B + (size_t)bR0 * ldb + g_kp + kb;
    const bf16* bP1 = B + (size_t)bR1 * ldb + g_kp + kb;

    f32x4_t acc[4][4];
    #pragma unroll
    for (int m = 0; m < 4; ++m)
        #pragma unroll
        for (int n = 0; n < 4; ++n)
            acc[m][n] = f32x4_t{0.f, 0.f, 0.f, 0.f};

    auto STAGE = [&](int buf, int k0) {
        __builtin_amdgcn_global_load_lds(AS1C(aP0 + k0), AS3C(&At[buf][wid * 32][0]),      16, 0, 0);
        __builtin_amdgcn_global_load_lds(AS1C(aP1 + k0), AS3C(&At[buf][wid * 32 + 16][0]), 16, 0, 0);
        __builtin_amdgcn_global_load_lds(AS1C(bP0 + k0), AS3C(&Bt[buf][wid * 32][0]),      16, 0, 0);
        __builtin_amdgcn_global_load_lds(AS1C(bP1 + k0), AS3C(&Bt[buf][wid * 32 + 16][0]), 16, 0, 0);
    };

    STAGE(0, 0);
    __syncthreads();                       // prologue drain: buf0 ready
    int cur = 0;
    for (int k0 = 0; k0 < K; k0 += 32) {
        if (k0 + 32 < K) STAGE(cur ^ 1, k0 + 32);   // issue next-tile loads FIRST

        bf16x8_t af[4], bg[4];
        #pragma unroll
        for (int m = 0; m < 4; ++m)
            af[m] = *(const bf16x8_t*)&At[cur][wr * 64 + m * 16 + fr][fq * 8];
        #pragma unroll
        for (int n = 0; n < 4; ++n)
            bg[n] = *(const bf16x8_t*)&Bt[cur][wc * 64 + n * 16 + fr][fq * 8];
        #pragma unroll
        for (int m = 0; m < 4; ++m)
            #pragma unroll
            for (int n = 0; n < 4; ++n)
                acc[m][n] = __builtin_amdgcn_mfma_f32_16x16x32_bf16(
                    af[m], bg[n], acc[m][n], 0, 0, 0);

        __syncthreads();                   // drains vmcnt: next buf landed; cur reads done
        cur ^= 1;
    }

    float* Cfz = SPLITK ? (Cf + (size_t)blockIdx.z * M * ldc) : Cf;

    // C/D layout: col = lane&15, row = (lane>>4)*4 + reg
    #pragma unroll
    for (int m = 0; m < 4; ++m) {
        #pragma unroll
        for (int n = 0; n < 4; ++n) {
            const int c = col0 + wc * 64 + n * 16 + fr;
            if (c < N) {
                #pragma unroll
                for (int r = 0; r < 4; ++r) {
                    const int rr = row0 + wr * 64 + m * 16 + fq * 4 + r;
                    if (SPLITK || MODE != 1) Cfz[(size_t)rr * ldc + c] = acc[m][n][r];
                    if (!SPLITK && MODE != 0) Cb[(size_t)rr * ldc + c] = __float2bfloat16(acc[m][n][r]);
                }
            }
        }
    }
}

// ---------------------------------------------------------------------------
// Reduce split-K partials (float4 per thread) -> optional f32 / bf16 outputs.
// ---------------------------------------------------------------------------
__global__ __launch_bounds__(256)
void reduce_pk(const float* __restrict__ part, float* __restrict__ of,
               bf16* __restrict__ oh, int n4, int stride4, int S)
{
    const int i = blockIdx.x * blockDim.x + threadIdx.x;
    if (i >= n4) return;
    const float4* p4 = (const float4*)part;
    float4 s = p4[i];
    for (int k = 1; k < S; ++k) {
        float4 v = p4[(size_t)k * stride4 + i];
        s.x += v.x; s.y += v.y; s.z += v.z; s.w += v.w;
    }
    if (of) ((float4*)of)[i] = s;
    if (oh) {
        bf16 o[4];
        o[0] = __float2bfloat16(s.x); o[1] = __float2bfloat16(s.y);
        o[2] = __float2bfloat16(s.z); o[3] = __float2bfloat16(s.w);
        *(int2*)(oh + (size_t)i * 4) = *(int2*)o;
    }
}

// ---------------------------------------------------------------------------
// Causal depthwise conv1d (width 4) + bias + SiLU; f32 in, bf16 out.
// ---------------------------------------------------------------------------
__global__ __launch_bounds__(256)
void conv_silu(const float* __restrict__ xz, const float* __restrict__ cw,
               const float* __restrict__ cb, bf16* __restrict__ xc,
               int Bsz, int L, int dinner)
{
    const int nv = dinner / 4;
    const int g  = blockIdx.x * blockDim.x + threadIdx.x;
    const int d4 = (g % nv) * 4;
    const int t  = (g / nv) % L;
    const int b  = g / (nv * L);
    if (b >= Bsz) return;

    const int ldxz = 2 * dinner;
    float4 w0 = *(const float4*)(cw + (size_t)(d4 + 0) * 4);
    float4 w1 = *(const float4*)(cw + (size_t)(d4 + 1) * 4);
    float4 w2 = *(const float4*)(cw + (size_t)(d4 + 2) * 4);
    float4 w3 = *(const float4*)(cw + (size_t)(d4 + 3) * 4);
    float4 acc = *(const float4*)(cb + d4);

    const float* base = xz + (size_t)b * L * ldxz + d4;
    #pragma unroll
    for (int k = 0; k < 4; ++k) {
        const int ts = t - 3 + k;
        if (ts >= 0) {
            float4 v = *(const float4*)(base + (size_t)ts * ldxz);
            acc.x = fmaf(v.x, (&w0.x)[k], acc.x);
            acc.y = fmaf(v.y, (&w1.x)[k], acc.y);
            acc.z = fmaf(v.z, (&w2.x)[k], acc.z);
            acc.w = fmaf(v.w, (&w3.x)[k], acc.w);
        }
    }
    acc.x = acc.x * frcp(1.f + fexp2(-acc.x * LOG2E));
    acc.y = acc.y * frcp(1.f + fexp2(-acc.y * LOG2E));
    acc.z = acc.z * frcp(1.f + fexp2(-acc.z * LOG2E));
    acc.w = acc.w * frcp(1.f + fexp2(-acc.w * LOG2E));

    bf16 o[4];
    o[0] = __float2bfloat16(acc.x); o[1] = __float2bfloat16(acc.y);
    o[2] = __float2bfloat16(acc.z); o[3] = __float2bfloat16(acc.w);
    *(int2*)(xc + ((size_t)b * L + t) * dinner + d4) = *(int2*)o;
}

// ---------------------------------------------------------------------------
// Chunked scan pass 1: lane owns 4 states of one d; local scan from h=0;
// emits chunk-final state and (sq==0) the softplus-sum S.
// ---------------------------------------------------------------------------
__global__ __launch_bounds__(256)
void scan_part1(const bf16* __restrict__ dtraw, const bf16* __restrict__ xc,
                const float* __restrict__ dbl, const float* __restrict__ dtb,
                const float* __restrict__ alog, float* __restrict__ hend,
                float* __restrict__ Ssum, int Bsz, int L, int dinner,
                int NC, int CL)
{
    const int g  = blockIdx.x * blockDim.x + threadIdx.x;
    const int sq = g & 3;
    const int d  = (g >> 2) % dinner;
    const int c  = ((g >> 2) / dinner) % NC;
    const int b  = g / (4 * dinner * NC);
    if (b >= Bsz) return;

    float4 av = *(const float4*)(alog + (size_t)d * 16 + sq * 4);
    const float As0 = -fexp2(av.x * LOG2E) * LOG2E;
    const float As1 = -fexp2(av.y * LOG2E) * LOG2E;
    const float As2 = -fexp2(av.z * LOG2E) * LOG2E;
    const float As3 = -fexp2(av.w * LOG2E) * LOG2E;
    const float bias = dtb[d];

    const int t0 = c * CL;
    const bf16*  dt_p = dtraw + ((size_t)b * L + t0) * dinner + d;
    const bf16*  xc_p = xc    + ((size_t)b * L + t0) * dinner + d;
    const float* bl_p = dbl   + ((size_t)b * L + t0) * 96 + 64 + sq * 4;

    float h0 = 0.f, h1 = 0.f, h2 = 0.f, h3 = 0.f, S = 0.f;
    for (int t = 0; t < CL; ++t) {
        const float dtv = __bfloat162float(*dt_p);
        const float xcv = __bfloat162float(*xc_p);
        const float4 Bv = *(const float4*)bl_p;

        const float xv = dtv + bias;
        const float e  = fexp2(xv * LOG2E);
        const float sp = (xv > 15.f) ? xv : LN2 * flog2(1.f + e);
        S += sp;
        const float u = sp * xcv;
        h0 = fmaf(fexp2(sp * As0), h0, u * Bv.x);
        h1 = fmaf(fexp2(sp * As1), h1, u * Bv.y);
        h2 = fmaf(fexp2(sp * As2), h2, u * Bv.z);
        h3 = fmaf(fexp2(sp * As3), h3, u * Bv.w);

        dt_p += dinner; xc_p += dinner; bl_p += 96;
    }

    const size_t idx = ((size_t)b * NC + c) * dinner + d;
    *(float4*)(hend + idx * 16 + sq * 4) = make_float4(h0, h1, h2, h3);
    if (sq == 0) Ssum[idx] = S;
}

// ---------------------------------------------------------------------------
// Chunk prefix: replaces hend IN PLACE with the EXCLUSIVE prefix state.
// ---------------------------------------------------------------------------
__global__ __launch_bounds__(256)
void chunk_prefix(float* __restrict__ hend, const float* __restrict__ Ssum,
                  const float* __restrict__ alog, int Bsz, int dinner, int NC)
{
    const int g = blockIdx.x * blockDim.x + threadIdx.x;
    const int s = g & 15;
    const int d = (g >> 4) % dinner;
    const int b = g / (16 * dinner);
    if (b >= Bsz) return;

    const float As2 = -fexp2(alog[(size_t)d * 16 + s] * LOG2E) * LOG2E;

    float h = 0.f;
    for (int c = 0; c < NC; ++c) {
        const size_t idx = ((size_t)b * NC + c) * dinner + d;
        const float he = hend[idx * 16 + s];
        const float Sv = Ssum[idx];
        hend[idx * 16 + s] = h;
        h = fmaf(fexp2(As2 * Sv), h, he);
    }
}

// ---------------------------------------------------------------------------
// Chunked scan pass 2: start from entry state, re-scan, reduce 16 states
// (4 in-lane + 2 shfl), D-skip, SiLU(z) gate; bf16 y in place over dt_raw.
// ---------------------------------------------------------------------------
__global__ __launch_bounds__(256)
void scan_part2(bf16* dty, const bf16* __restrict__ xc,
                const float* __restrict__ dbl, const float* __restrict__ xz,
                const float* __restrict__ dtb, const float* __restrict__ alog,
                const float* __restrict__ Dp, const float* __restrict__ hinit,
                int Bsz, int L, int dinner, int NC, int CL)
{
    const int g  = blockIdx.x * blockDim.x + threadIdx.x;
    const int sq = g & 3;
    const int d  = (g >> 2) % dinner;
    const int c  = ((g >> 2) / dinner) % NC;
    const int b  = g / (4 * dinner * NC);
    if (b >= Bsz) return;

    float4 av = *(const float4*)(alog + (size_t)d * 16 + sq * 4);
    const float As0 = -fexp2(av.x * LOG2E) * LOG2E;
    const float As1 = -fexp2(av.y * LOG2E) * LOG2E;
    const float As2 = -fexp2(av.z * LOG2E) * LOG2E;
    const float As3 = -fexp2(av.w * LOG2E) * LOG2E;
    const float bias = dtb[d];
    const float Dval = Dp[d];

    const size_t cidx = ((size_t)b * NC + c) * dinner + d;
    float4 hv = *(const float4*)(hinit + cidx * 16 + sq * 4);
    float h0 = hv.x, h1 = hv.y, h2 = hv.z, h3 = hv.w;

    const int t0 = c * CL;
    bf16*        dt_p = dty + ((size_t)b * L + t0) * dinner + d;
    const bf16*  xc_p = xc  + ((size_t)b * L + t0) * dinner + d;
    const float* bl_p = dbl + ((size_t)b * L + t0) * 96 + 64 + sq * 4;
    const float* z_p  = xz  + ((size_t)b * L + t0) * (2 * dinner) + dinner + d;

    for (int t = 0; t < CL; ++t) {
        const float dtv = __bfloat162float(*dt_p);
        const float xcv = __bfloat162float(*xc_p);
        const float4 Bv = *(const float4*)bl_p;
        const float4 Cv = *(const float4*)(bl_p + 16);
        const float zv  = *z_p;

        const float xv = dtv + bias;
        const float e  = fexp2(xv * LOG2E);
        const float sp = (xv > 15.f) ? xv : LN2 * flog2(1.f + e);
        const float u = sp * xcv;
        h0 = fmaf(fexp2(sp * As0), h0, u * Bv.x);
        h1 = fmaf(fexp2(sp * As1), h1, u * Bv.y);
        h2 = fmaf(fexp2(sp * As2), h2, u * Bv.z);
        h3 = fmaf(fexp2(sp * As3), h3, u * Bv.w);

        float y = h0 * Cv.x + h1 * Cv.y + h2 * Cv.z + h3 * Cv.w;
        y += __shfl_xor(y, 1, 4);
        y += __shfl_xor(y, 2, 4);

        if (sq == 0) {
            y = fmaf(xcv, Dval, y);
            const float sig = frcp(1.f + fexp2(-zv * LOG2E));
            *dt_p = __float2bfloat16(y * (zv * sig));
        }

        dt_p += dinner; xc_p += dinner; bl_p += 96; z_p += 2 * dinner;
    }
}

// ---------------------------------------------------------------------------
extern "C" void kernel_launch(void* const* d_in, const int* in_sizes, int n_in,
                              void* d_out, int out_size, void* d_ws, size_t ws_size,
                              hipStream_t stream)
{
    const float* x    = (const float*)d_in[0];
    const float* inw  = (const float*)d_in[1];
    const float* cw   = (const float*)d_in[2];
    const float* cb   = (const float*)d_in[3];
    const float* xw   = (const float*)d_in[4];
    const float* dtw  = (const float*)d_in[5];
    const float* dtb  = (const float*)d_in[6];
    const float* alog = (const float*)d_in[7];
    const float* Dp   = (const float*)d_in[8];
    const float* ow   = (const float*)d_in[9];
    float* out = (float*)d_out;

    const int Bsz = 2, L = 1024, dmodel = 1024, dinner = 2048;
    const int BL = Bsz * L;            // 2048
    const int NC = 32, CL = L / NC;    // 32 chunks of 32
    const int SPX = 8,  KSX = dinner / SPX;   // x_proj split-K
    const int SPO = 2,  KSO = dinner / SPO;   // out_proj split-K

    // --- workspace layout ---------------------------------------------------
    char* p = (char*)d_ws;
    auto alloc = [&](size_t bytes) { char* r = p; p += (bytes + 63) & ~size_t(63); return r; };
    bf16*  wb_in  = (bf16*) alloc((size_t)2 * 2 * dinner * dmodel * 2);   // both layers
    bf16*  wb_x   = (bf16*) alloc((size_t)2 * 96 * dinner * 2);
    bf16*  wb_dt  = (bf16*) alloc((size_t)2 * dinner * 64 * 2);
    bf16*  wb_ow  = (bf16*) alloc((size_t)2 * dmodel * dinner * 2);
    bf16*  curb   = (bf16*) alloc((size_t)BL * dmodel * 2);
    float* xzb    = (float*)alloc((size_t)BL * 2 * dinner * 4);
    bf16*  xcb16  = (bf16*) alloc((size_t)BL * dinner * 2);
    float* dblb   = (float*)alloc((size_t)BL * 96 * 4);
    bf16*  dblb16 = (bf16*) alloc((size_t)BL * 96 * 2);
    bf16*  dtrb16 = (bf16*) alloc((size_t)BL * dinner * 2);
    float* hendb  = (float*)alloc((size_t)Bsz * NC * dinner * 16 * 4);
    float* ssumb  = (float*)alloc((size_t)Bsz * NC * dinner * 4);
    // shared split-K partial scratch: max(x_proj 8*2048*96, out_proj 2*2048*1024) f32
    float* partb  = (float*)alloc((size_t)SPO * BL * dmodel * 4);

    const int scan_blocks = (Bsz * NC * dinner * 4) / 256;    // 2048
    const int pfx_blocks  = (Bsz * dinner * 16) / 256;        // 256

    // ---- all casts up front (weights are layer-contiguous) ----
    cast_f32_bf16<<<(BL * dmodel / 8) / 256, 256, 0, stream>>>(x, curb, BL * dmodel / 8);
    cast_f32_bf16<<<(2 * 2 * dinner * dmodel / 8) / 256, 256, 0, stream>>>(
        inw, wb_in, 2 * 2 * dinner * dmodel / 8);
    cast_f32_bf16<<<(2 * 96 * dinner / 8) / 256, 256, 0, stream>>>(
        xw, wb_x, 2 * 96 * dinner / 8);
    cast_f32_bf16<<<(2 * dinner * 64 / 8) / 256, 256, 0, stream>>>(
        dtw, wb_dt, 2 * dinner * 64 / 8);
    cast_f32_bf16<<<(2 * dmodel * dinner / 8) / 256, 256, 0, stream>>>(
        ow, wb_ow, 2 * dmodel * dinner / 8);

    for (int l = 0; l < 2; ++l) {
        const bf16*  wb_in_l = wb_in + (size_t)l * 2 * dinner * dmodel;
        const bf16*  wb_x_l  = wb_x  + (size_t)l * 96 * dinner;
        const bf16*  wb_dt_l = wb_dt + (size_t)l * dinner * 64;
        const bf16*  wb_ow_l = wb_ow + (size_t)l * dmodel * dinner;
        const float* cw_l    = cw   + (size_t)l * dinner * 4;
        const float* cb_l    = cb   + (size_t)l * dinner;
        const float* dtb_l   = dtb  + (size_t)l * dinner;
        const float* alog_l  = alog + (size_t)l * dinner * 16;
        const float* Dp_l    = Dp   + (size_t)l * dinner;

        // 1) xz = cur @ in_w^T   (2048 x 4096, K=1024) -> f32
        gemm_bf16<0, false><<<dim3(2 * dinner / 128, BL / 128), 256, 0, stream>>>(
            curb, wb_in_l, xzb, nullptr, BL, 2 * dinner, dmodel, dmodel, dmodel, 2 * dinner);

        // 2) xc = silu(conv(xr) + cb) -> bf16
        conv_silu<<<(BL * dinner / 4) / 256, 256, 0, stream>>>(
            xzb, cw_l, cb_l, xcb16, Bsz, L, dinner);

        // 3) dbl = xc @ xw^T     (2048 x 96, K=2048), split-K x8 + reduce
        gemm_bf16<0, true><<<dim3(1, BL / 128, SPX), 256, 0, stream>>>(
            xcb16, wb_x_l, partb, nullptr, BL, 96, KSX, dinner, dinner, 96);
        reduce_pk<<<(BL * 96 / 4 + 255) / 256, 256, 0, stream>>>(
            partb, dblb, dblb16, BL * 96 / 4, BL * 96 / 4, SPX);

        // 4) dt_raw = dbl[:, :64] @ dtw^T  (2048 x 2048, K=64) -> bf16
        gemm_bf16<1, false><<<dim3(dinner / 128, BL / 128), 256, 0, stream>>>(
            dblb16, wb_dt_l, nullptr, dtrb16, BL, dinner, 64, 96, 64, dinner);

        // 5) chunked scan: local scans -> chunk prefix -> final pass
        scan_part1<<<scan_blocks, 256, 0, stream>>>(
            dtrb16, xcb16, dblb, dtb_l, alog_l, hendb, ssumb, Bsz, L, dinner, NC, CL);
        chunk_prefix<<<pfx_blocks, 256, 0, stream>>>(
            hendb, ssumb, alog_l, Bsz, dinner, NC);
        scan_part2<<<scan_blocks, 256, 0, stream>>>(
            dtrb16, xcb16, dblb, xzb, dtb_l, alog_l, Dp_l, hendb,
            Bsz, L, dinner, NC, CL);

        // 6) out = y @ ow^T      (2048 x 1024, K=2048), split-K x2 + reduce
        gemm_bf16<0, true><<<dim3(dmodel / 128, BL / 128, SPO), 256, 0, stream>>>(
            dtrb16, wb_ow_l, partb, nullptr, BL, dmodel, KSO, dinner, dinner, dmodel);
        if (l == 0)
            reduce_pk<<<(BL * dmodel / 4 + 255) / 256, 256, 0, stream>>>(
                partb, nullptr, curb, BL * dmodel / 4, BL * dmodel / 4, SPO);
        else
            reduce_pk<<<(BL * dmodel / 4 + 255) / 256, 256, 0, stream>>>(
                partb, out, nullptr, BL * dmodel / 4, BL * dmodel / 4, SPO);
    }
}

// Round 8
// 331.359 us; speedup vs baseline: 9.6501x; 1.0350x over previous
//
#include <hip/hip_runtime.h>
#include <hip/hip_bf16.h>
#include <cmath>

typedef __bf16 bf16x8_t __attribute__((ext_vector_type(8)));
typedef float  f32x4_t  __attribute__((ext_vector_type(4)));
using bf16 = __hip_bfloat16;

#define LOG2E 1.44269504088896340736f
#define LN2   0.69314718055994530942f

#define AS1C(p) ((const __attribute__((address_space(1))) void*)(p))
#define AS3C(p) ((__attribute__((address_space(3))) void*)(p))

__device__ __forceinline__ float fexp2(float x) { return __builtin_amdgcn_exp2f(x); }
__device__ __forceinline__ float flog2(float x) { return __builtin_amdgcn_logf(x); }
__device__ __forceinline__ float frcp (float x) { return __builtin_amdgcn_rcpf(x); }

// ---------------------------------------------------------------------------
// Fused multi-tensor f32 -> bf16 cast. 5 segments, one dispatch.
// Every segment's n8 is a multiple of 256 (no bounds checks needed).
// e_i = cumulative END block of segment i.
// ---------------------------------------------------------------------------
__global__ __launch_bounds__(256)
void cast_multi(const float* s0, bf16* d0, int e0,
                const float* s1, bf16* d1, int e1,
                const float* s2, bf16* d2, int e2,
                const float* s3, bf16* d3, int e3,
                const float* s4, bf16* d4, int e4)
{
    const int blk = blockIdx.x;
    const float* src; bf16* dst; int base;
    if      (blk < e0) { src = s0; dst = d0; base = blk; }
    else if (blk < e1) { src = s1; dst = d1; base = blk - e0; }
    else if (blk < e2) { src = s2; dst = d2; base = blk - e1; }
    else if (blk < e3) { src = s3; dst = d3; base = blk - e2; }
    else               { src = s4; dst = d4; base = blk - e3; }

    const int i = base * 256 + threadIdx.x;
    const float4* s = (const float4*)(src + (size_t)i * 8);
    float4 a = s[0], b = s[1];
    bf16 o[8];
    o[0] = __float2bfloat16(a.x); o[1] = __float2bfloat16(a.y);
    o[2] = __float2bfloat16(a.z); o[3] = __float2bfloat16(a.w);
    o[4] = __float2bfloat16(b.x); o[5] = __float2bfloat16(b.y);
    o[6] = __float2bfloat16(b.z); o[7] = __float2bfloat16(b.w);
    *(int4*)(dst + (size_t)i * 8) = *(int4*)o;
}

// ---------------------------------------------------------------------------
// bf16 MFMA NT GEMM, 2-phase double-buffered async staging.
// C[M,N] = A[M,K] * B[N,K]^T. BM=BN=128, BK=32, 4 waves x (64x64).
// Loop: STAGE(next) -> ds_read+MFMA(cur) -> __syncthreads (drains vmcnt).
// SPLITK: blockIdx.z selects a K-segment; f32 partial to Cf + z*M*ldc.
// MODE: 0 = f32 store, 1 = bf16 store (ignored when SPLITK).
// ---------------------------------------------------------------------------
template<int MODE, bool SPLITK>
__global__ __launch_bounds__(256)
void gemm_bf16(const bf16* __restrict__ A, const bf16* __restrict__ B,
               float* __restrict__ Cf, bf16* __restrict__ Cb,
               int M, int N, int K, int lda, int ldb, int ldc)
{
    __shared__ __align__(16) bf16 At[2][128][32];
    __shared__ __align__(16) bf16 Bt[2][128][32];

    const int tid  = threadIdx.x;
    const int lane = tid & 63;
    const int wid  = tid >> 6;
    const int wr   = wid >> 1;
    const int wc   = wid & 1;
    const int fr   = lane & 15;
    const int fq   = lane >> 4;

    const int row0 = blockIdx.y * 128;
    const int col0 = blockIdx.x * 128;
    const int kb   = SPLITK ? blockIdx.z * K : 0;

    const int g_row = wid * 32 + (lane >> 2);
    const int g_kp  = (lane & 3) * 8;
    const bf16* aP0 = A + (size_t)(row0 + g_row) * lda + g_kp + kb;
    const bf16* aP1 = A + (size_t)(row0 + g_row + 16) * lda + g_kp + kb;
    int bR0 = col0 + g_row;      if (bR0 >= N) bR0 = N - 1;
    int bR1 = col0 + g_row + 16; if (bR1 >= N) bR1 = N - 1;
    const bf16* bP0 = B + (size_t)bR0 * ldb + g_kp + kb;
    const bf16* bP1 = B + (size_t)bR1 * ldb + g_kp + kb;

    f32x4_t acc[4][4];
    #pragma unroll
    for (int m = 0; m < 4; ++m)
        #pragma unroll
        for (int n = 0; n < 4; ++n)
            acc[m][n] = f32x4_t{0.f, 0.f, 0.f, 0.f};

    auto STAGE = [&](int buf, int k0) {
        __builtin_amdgcn_global_load_lds(AS1C(aP0 + k0), AS3C(&At[buf][wid * 32][0]),      16, 0, 0);
        __builtin_amdgcn_global_load_lds(AS1C(aP1 + k0), AS3C(&At[buf][wid * 32 + 16][0]), 16, 0, 0);
        __builtin_amdgcn_global_load_lds(AS1C(bP0 + k0), AS3C(&Bt[buf][wid * 32][0]),      16, 0, 0);
        __builtin_amdgcn_global_load_lds(AS1C(bP1 + k0), AS3C(&Bt[buf][wid * 32 + 16][0]), 16, 0, 0);
    };

    STAGE(0, 0);
    __syncthreads();
    int cur = 0;
    for (int k0 = 0; k0 < K; k0 += 32) {
        if (k0 + 32 < K) STAGE(cur ^ 1, k0 + 32);

        bf16x8_t af[4], bg[4];
        #pragma unroll
        for (int m = 0; m < 4; ++m)
            af[m] = *(const bf16x8_t*)&At[cur][wr * 64 + m * 16 + fr][fq * 8];
        #pragma unroll
        for (int n = 0; n < 4; ++n)
            bg[n] = *(const bf16x8_t*)&Bt[cur][wc * 64 + n * 16 + fr][fq * 8];
        #pragma unroll
        for (int m = 0; m < 4; ++m)
            #pragma unroll
            for (int n = 0; n < 4; ++n)
                acc[m][n] = __builtin_amdgcn_mfma_f32_16x16x32_bf16(
                    af[m], bg[n], acc[m][n], 0, 0, 0);

        __syncthreads();
        cur ^= 1;
    }

    float* Cfz = SPLITK ? (Cf + (size_t)blockIdx.z * M * ldc) : Cf;

    // C/D layout: col = lane&15, row = (lane>>4)*4 + reg
    #pragma unroll
    for (int m = 0; m < 4; ++m) {
        #pragma unroll
        for (int n = 0; n < 4; ++n) {
            const int c = col0 + wc * 64 + n * 16 + fr;
            if (c < N) {
                #pragma unroll
                for (int r = 0; r < 4; ++r) {
                    const int rr = row0 + wr * 64 + m * 16 + fq * 4 + r;
                    if (SPLITK || MODE != 1) Cfz[(size_t)rr * ldc + c] = acc[m][n][r];
                    if (!SPLITK && MODE != 0) Cb[(size_t)rr * ldc + c] = __float2bfloat16(acc[m][n][r]);
                }
            }
        }
    }
}

// ---------------------------------------------------------------------------
// Reduce split-K partials (float4 per thread) -> optional f32 / bf16 outputs.
// ---------------------------------------------------------------------------
__global__ __launch_bounds__(256)
void reduce_pk(const float* __restrict__ part, float* __restrict__ of,
               bf16* __restrict__ oh, int n4, int stride4, int S)
{
    const int i = blockIdx.x * blockDim.x + threadIdx.x;
    if (i >= n4) return;
    const float4* p4 = (const float4*)part;
    float4 s = p4[i];
    for (int k = 1; k < S; ++k) {
        float4 v = p4[(size_t)k * stride4 + i];
        s.x += v.x; s.y += v.y; s.z += v.z; s.w += v.w;
    }
    if (of) ((float4*)of)[i] = s;
    if (oh) {
        bf16 o[4];
        o[0] = __float2bfloat16(s.x); o[1] = __float2bfloat16(s.y);
        o[2] = __float2bfloat16(s.z); o[3] = __float2bfloat16(s.w);
        *(int2*)(oh + (size_t)i * 4) = *(int2*)o;
    }
}

// ---------------------------------------------------------------------------
// Causal depthwise conv1d (width 4) + bias + SiLU; bf16 xz in, bf16 xc out.
// ---------------------------------------------------------------------------
__global__ __launch_bounds__(256)
void conv_silu(const bf16* __restrict__ xz, const float* __restrict__ cw,
               const float* __restrict__ cb, bf16* __restrict__ xc,
               int Bsz, int L, int dinner)
{
    const int nv = dinner / 4;
    const int g  = blockIdx.x * blockDim.x + threadIdx.x;
    const int d4 = (g % nv) * 4;
    const int t  = (g / nv) % L;
    const int b  = g / (nv * L);
    if (b >= Bsz) return;

    const int ldxz = 2 * dinner;
    float4 w0 = *(const float4*)(cw + (size_t)(d4 + 0) * 4);
    float4 w1 = *(const float4*)(cw + (size_t)(d4 + 1) * 4);
    float4 w2 = *(const float4*)(cw + (size_t)(d4 + 2) * 4);
    float4 w3 = *(const float4*)(cw + (size_t)(d4 + 3) * 4);
    float4 acc = *(const float4*)(cb + d4);

    const bf16* base = xz + (size_t)b * L * ldxz + d4;
    #pragma unroll
    for (int k = 0; k < 4; ++k) {
        const int ts = t - 3 + k;
        if (ts >= 0) {
            const bf16* rp = base + (size_t)ts * ldxz;
            float vx = __bfloat162float(rp[0]);
            float vy = __bfloat162float(rp[1]);
            float vz = __bfloat162float(rp[2]);
            float vw = __bfloat162float(rp[3]);
            acc.x = fmaf(vx, (&w0.x)[k], acc.x);
            acc.y = fmaf(vy, (&w1.x)[k], acc.y);
            acc.z = fmaf(vz, (&w2.x)[k], acc.z);
            acc.w = fmaf(vw, (&w3.x)[k], acc.w);
        }
    }
    acc.x = acc.x * frcp(1.f + fexp2(-acc.x * LOG2E));
    acc.y = acc.y * frcp(1.f + fexp2(-acc.y * LOG2E));
    acc.z = acc.z * frcp(1.f + fexp2(-acc.z * LOG2E));
    acc.w = acc.w * frcp(1.f + fexp2(-acc.w * LOG2E));

    bf16 o[4];
    o[0] = __float2bfloat16(acc.x); o[1] = __float2bfloat16(acc.y);
    o[2] = __float2bfloat16(acc.z); o[3] = __float2bfloat16(acc.w);
    *(int2*)(xc + ((size_t)b * L + t) * dinner + d4) = *(int2*)o;
}

// ---------------------------------------------------------------------------
// Chunked scan pass 1: lane owns 4 states of one d; local scan from h=0;
// emits chunk-final state and (sq==0) the softplus-sum S.
// ---------------------------------------------------------------------------
__global__ __launch_bounds__(256)
void scan_part1(const bf16* __restrict__ dtraw, const bf16* __restrict__ xc,
                const float* __restrict__ dbl, const float* __restrict__ dtb,
                const float* __restrict__ alog, float* __restrict__ hend,
                float* __restrict__ Ssum, int Bsz, int L, int dinner,
                int NC, int CL)
{
    const int g  = blockIdx.x * blockDim.x + threadIdx.x;
    const int sq = g & 3;
    const int d  = (g >> 2) % dinner;
    const int c  = ((g >> 2) / dinner) % NC;
    const int b  = g / (4 * dinner * NC);
    if (b >= Bsz) return;

    float4 av = *(const float4*)(alog + (size_t)d * 16 + sq * 4);
    const float As0 = -fexp2(av.x * LOG2E) * LOG2E;
    const float As1 = -fexp2(av.y * LOG2E) * LOG2E;
    const float As2 = -fexp2(av.z * LOG2E) * LOG2E;
    const float As3 = -fexp2(av.w * LOG2E) * LOG2E;
    const float bias = dtb[d];

    const int t0 = c * CL;
    const bf16*  dt_p = dtraw + ((size_t)b * L + t0) * dinner + d;
    const bf16*  xc_p = xc    + ((size_t)b * L + t0) * dinner + d;
    const float* bl_p = dbl   + ((size_t)b * L + t0) * 96 + 64 + sq * 4;

    float h0 = 0.f, h1 = 0.f, h2 = 0.f, h3 = 0.f, S = 0.f;
    for (int t = 0; t < CL; ++t) {
        const float dtv = __bfloat162float(*dt_p);
        const float xcv = __bfloat162float(*xc_p);
        const float4 Bv = *(const float4*)bl_p;

        const float xv = dtv + bias;
        const float e  = fexp2(xv * LOG2E);
        const float sp = (xv > 15.f) ? xv : LN2 * flog2(1.f + e);
        S += sp;
        const float u = sp * xcv;
        h0 = fmaf(fexp2(sp * As0), h0, u * Bv.x);
        h1 = fmaf(fexp2(sp * As1), h1, u * Bv.y);
        h2 = fmaf(fexp2(sp * As2), h2, u * Bv.z);
        h3 = fmaf(fexp2(sp * As3), h3, u * Bv.w);

        dt_p += dinner; xc_p += dinner; bl_p += 96;
    }

    const size_t idx = ((size_t)b * NC + c) * dinner + d;
    *(float4*)(hend + idx * 16 + sq * 4) = make_float4(h0, h1, h2, h3);
    if (sq == 0) Ssum[idx] = S;
}

// ---------------------------------------------------------------------------
// Chunked scan pass 2 (with inlined chunk-prefix composition): build entry
// state from chunk summaries 0..c-1, re-scan the chunk, reduce 16 states
// (4 in-lane + 2 shfl), D-skip, SiLU(z) gate; bf16 y in place over dt_raw.
// ---------------------------------------------------------------------------
__global__ __launch_bounds__(256)
void scan_part2(bf16* dty, const bf16* __restrict__ xc,
                const float* __restrict__ dbl, const bf16* __restrict__ xz,
                const float* __restrict__ dtb, const float* __restrict__ alog,
                const float* __restrict__ Dp, const float* __restrict__ hend,
                const float* __restrict__ Ssum,
                int Bsz, int L, int dinner, int NC, int CL)
{
    const int g  = blockIdx.x * blockDim.x + threadIdx.x;
    const int sq = g & 3;
    const int d  = (g >> 2) % dinner;
    const int c  = ((g >> 2) / dinner) % NC;
    const int b  = g / (4 * dinner * NC);
    if (b >= Bsz) return;

    float4 av = *(const float4*)(alog + (size_t)d * 16 + sq * 4);
    const float As0 = -fexp2(av.x * LOG2E) * LOG2E;
    const float As1 = -fexp2(av.y * LOG2E) * LOG2E;
    const float As2 = -fexp2(av.z * LOG2E) * LOG2E;
    const float As3 = -fexp2(av.w * LOG2E) * LOG2E;
    const float bias = dtb[d];
    const float Dval = Dp[d];

    // compose entry state from previous chunk summaries
    float h0 = 0.f, h1 = 0.f, h2 = 0.f, h3 = 0.f;
    for (int cp = 0; cp < c; ++cp) {
        const size_t idx = ((size_t)b * NC + cp) * dinner + d;
        const float4 he = *(const float4*)(hend + idx * 16 + sq * 4);
        const float  Sv = Ssum[idx];
        h0 = fmaf(fexp2(As0 * Sv), h0, he.x);
        h1 = fmaf(fexp2(As1 * Sv), h1, he.y);
        h2 = fmaf(fexp2(As2 * Sv), h2, he.z);
        h3 = fmaf(fexp2(As3 * Sv), h3, he.w);
    }

    const int t0 = c * CL;
    bf16*        dt_p = dty + ((size_t)b * L + t0) * dinner + d;
    const bf16*  xc_p = xc  + ((size_t)b * L + t0) * dinner + d;
    const float* bl_p = dbl + ((size_t)b * L + t0) * 96 + 64 + sq * 4;
    const bf16*  z_p  = xz  + ((size_t)b * L + t0) * (2 * dinner) + dinner + d;

    for (int t = 0; t < CL; ++t) {
        const float dtv = __bfloat162float(*dt_p);
        const float xcv = __bfloat162float(*xc_p);
        const float4 Bv = *(const float4*)bl_p;
        const float4 Cv = *(const float4*)(bl_p + 16);
        const float zv  = __bfloat162float(*z_p);

        const float xv = dtv + bias;
        const float e  = fexp2(xv * LOG2E);
        const float sp = (xv > 15.f) ? xv : LN2 * flog2(1.f + e);
        const float u = sp * xcv;
        h0 = fmaf(fexp2(sp * As0), h0, u * Bv.x);
        h1 = fmaf(fexp2(sp * As1), h1, u * Bv.y);
        h2 = fmaf(fexp2(sp * As2), h2, u * Bv.z);
        h3 = fmaf(fexp2(sp * As3), h3, u * Bv.w);

        float y = h0 * Cv.x + h1 * Cv.y + h2 * Cv.z + h3 * Cv.w;
        y += __shfl_xor(y, 1, 4);
        y += __shfl_xor(y, 2, 4);

        if (sq == 0) {
            y = fmaf(xcv, Dval, y);
            const float sig = frcp(1.f + fexp2(-zv * LOG2E));
            *dt_p = __float2bfloat16(y * (zv * sig));
        }

        dt_p += dinner; xc_p += dinner; bl_p += 96; z_p += 2 * dinner;
    }
}

// ---------------------------------------------------------------------------
extern "C" void kernel_launch(void* const* d_in, const int* in_sizes, int n_in,
                              void* d_out, int out_size, void* d_ws, size_t ws_size,
                              hipStream_t stream)
{
    const float* x    = (const float*)d_in[0];
    const float* inw  = (const float*)d_in[1];
    const float* cw   = (const float*)d_in[2];
    const float* cb   = (const float*)d_in[3];
    const float* xw   = (const float*)d_in[4];
    const float* dtw  = (const float*)d_in[5];
    const float* dtb  = (const float*)d_in[6];
    const float* alog = (const float*)d_in[7];
    const float* Dp   = (const float*)d_in[8];
    const float* ow   = (const float*)d_in[9];
    float* out = (float*)d_out;

    const int Bsz = 2, L = 1024, dmodel = 1024, dinner = 2048;
    const int BL = Bsz * L;            // 2048
    const int NC = 32, CL = L / NC;    // 32 chunks of 32
    const int SPX = 16, KSX = dinner / SPX;   // x_proj split-K
    const int SPO = 2,  KSO = dinner / SPO;   // out_proj split-K

    // --- workspace layout ---------------------------------------------------
    char* p = (char*)d_ws;
    auto alloc = [&](size_t bytes) { char* r = p; p += (bytes + 63) & ~size_t(63); return r; };
    bf16*  wb_in  = (bf16*) alloc((size_t)2 * 2 * dinner * dmodel * 2);   // both layers
    bf16*  wb_x   = (bf16*) alloc((size_t)2 * 96 * dinner * 2);
    bf16*  wb_dt  = (bf16*) alloc((size_t)2 * dinner * 64 * 2);
    bf16*  wb_ow  = (bf16*) alloc((size_t)2 * dmodel * dinner * 2);
    bf16*  curb   = (bf16*) alloc((size_t)BL * dmodel * 2);
    bf16*  xzb16  = (bf16*) alloc((size_t)BL * 2 * dinner * 2);           // xz bf16
    bf16*  xcb16  = (bf16*) alloc((size_t)BL * dinner * 2);
    float* dblb   = (float*)alloc((size_t)BL * 96 * 4);
    bf16*  dblb16 = (bf16*) alloc((size_t)BL * 96 * 2);
    bf16*  dtrb16 = (bf16*) alloc((size_t)BL * dinner * 2);
    float* hendb  = (float*)alloc((size_t)Bsz * NC * dinner * 16 * 4);
    float* ssumb  = (float*)alloc((size_t)Bsz * NC * dinner * 4);
    float* partb  = (float*)alloc((size_t)SPO * BL * dmodel * 4);         // shared PK scratch

    const int scan_blocks = (Bsz * NC * dinner * 4) / 256;    // 2048

    // ---- one fused cast dispatch (input + all weights, both layers) --------
    {
        const int n8_x  = BL * dmodel / 8;                 // 262144 -> 1024 blks
        const int n8_in = 2 * 2 * dinner * dmodel / 8;     // 1048576 -> 4096
        const int n8_xw = 2 * 96 * dinner / 8;             // 49152  -> 192
        const int n8_dt = 2 * dinner * 64 / 8;             // 32768  -> 128
        const int n8_ow = 2 * dmodel * dinner / 8;         // 524288 -> 2048
        const int e0 = n8_x / 256;
        const int e1 = e0 + n8_in / 256;
        const int e2 = e1 + n8_xw / 256;
        const int e3 = e2 + n8_dt / 256;
        const int e4 = e3 + n8_ow / 256;
        cast_multi<<<e4, 256, 0, stream>>>(
            x, curb, e0, inw, wb_in, e1, xw, wb_x, e2, dtw, wb_dt, e3, ow, wb_ow, e4);
    }

    for (int l = 0; l < 2; ++l) {
        const bf16*  wb_in_l = wb_in + (size_t)l * 2 * dinner * dmodel;
        const bf16*  wb_x_l  = wb_x  + (size_t)l * 96 * dinner;
        const bf16*  wb_dt_l = wb_dt + (size_t)l * dinner * 64;
        const bf16*  wb_ow_l = wb_ow + (size_t)l * dmodel * dinner;
        const float* cw_l    = cw   + (size_t)l * dinner * 4;
        const float* cb_l    = cb   + (size_t)l * dinner;
        const float* dtb_l   = dtb  + (size_t)l * dinner;
        const float* alog_l  = alog + (size_t)l * dinner * 16;
        const float* Dp_l    = Dp   + (size_t)l * dinner;

        // 1) xz = cur @ in_w^T   (2048 x 4096, K=1024) -> bf16
        gemm_bf16<1, false><<<dim3(2 * dinner / 128, BL / 128), 256, 0, stream>>>(
            curb, wb_in_l, nullptr, xzb16, BL, 2 * dinner, dmodel, dmodel, dmodel, 2 * dinner);

        // 2) xc = silu(conv(xr) + cb) -> bf16
        conv_silu<<<(BL * dinner / 4) / 256, 256, 0, stream>>>(
            xzb16, cw_l, cb_l, xcb16, Bsz, L, dinner);

        // 3) dbl = xc @ xw^T     (2048 x 96, K=2048), split-K x16 + reduce
        gemm_bf16<0, true><<<dim3(1, BL / 128, SPX), 256, 0, stream>>>(
            xcb16, wb_x_l, partb, nullptr, BL, 96, KSX, dinner, dinner, 96);
        reduce_pk<<<(BL * 96 / 4 + 255) / 256, 256, 0, stream>>>(
            partb, dblb, dblb16, BL * 96 / 4, BL * 96 / 4, SPX);

        // 4) dt_raw = dbl[:, :64] @ dtw^T  (2048 x 2048, K=64) -> bf16
        gemm_bf16<1, false><<<dim3(dinner / 128, BL / 128), 256, 0, stream>>>(
            dblb16, wb_dt_l, nullptr, dtrb16, BL, dinner, 64, 96, 64, dinner);

        // 5) chunked scan: local scans -> final pass (prefix inlined)
        scan_part1<<<scan_blocks, 256, 0, stream>>>(
            dtrb16, xcb16, dblb, dtb_l, alog_l, hendb, ssumb, Bsz, L, dinner, NC, CL);
        scan_part2<<<scan_blocks, 256, 0, stream>>>(
            dtrb16, xcb16, dblb, xzb16, dtb_l, alog_l, Dp_l, hendb, ssumb,
            Bsz, L, dinner, NC, CL);

        // 6) out = y @ ow^T      (2048 x 1024, K=2048), split-K x2 + reduce
        gemm_bf16<0, true><<<dim3(dmodel / 128, BL / 128, SPO), 256, 0, stream>>>(
            dtrb16, wb_ow_l, partb, nullptr, BL, dmodel, KSO, dinner, dinner, dmodel);
        if (l == 0)
            reduce_pk<<<(BL * dmodel / 4 + 255) / 256, 256, 0, stream>>>(
                partb, nullptr, curb, BL * dmodel / 4, BL * dmodel / 4, SPO);
        else
            reduce_pk<<<(BL * dmodel / 4 + 255) / 256, 256, 0, stream>>>(
                partb, out, nullptr, BL * dmodel / 4, BL * dmodel / 4, SPO);
    }
}